// Round 14
// baseline (273.078 us; speedup 1.0000x reference)
//
#include <hip/hip_runtime.h>

// SelfAttention: x[8,2048,512] f32, W[3,512,512] f32 -> out[8,2048,512] f32
// scale = 1/sqrt(64) = 0.125
//
// R14: (1) rowsum moved from pv's mainloop (64 VALU/thread/slab = 512cyc/
// SIMD/slab > MFMA 320cyc -> VALUBusy 35%) to scores' epilogue (one-time
// shfl reduce + atomicAdd into rsum[8][2048] f32 in the ws tail, zeroed by
// convert_x). pv fast path reads 1/rsum in epilogue. Fallback to R13's
// in-loop sum if ws too small. (2) 256x128 mainloop gets the ping-pong
// (proven on 256sq in R13: +13%), occupancy PRESERVED (bounds(512,4),
// VGPR ~92 < 128, 2 blk/CU) - R11's confound removed.

typedef unsigned short u16;
typedef unsigned int u32;

using bf16x8 = __attribute__((ext_vector_type(8))) short;   // 8 bf16 (4 VGPRs)
using f32x4  = __attribute__((ext_vector_type(4))) float;
using u16x4  = __attribute__((ext_vector_type(4))) u16;

__device__ __forceinline__ u16 f2bf(float f) {
  u32 u = __float_as_uint(f);
  u32 r = (u + 0x7FFFu + ((u >> 16) & 1u)) >> 16;   // RNE
  return (u16)r;
}
__device__ __forceinline__ float bf2f(u16 h) {
  return __uint_as_float(((u32)h) << 16);
}

#define GLL16(src, dst)                                                        \
  __builtin_amdgcn_global_load_lds(                                            \
      (const __attribute__((address_space(1))) void*)(src),                    \
      (__attribute__((address_space(3))) void*)(dst), 16, 0, 0)

// ---------------------------------------------------------------------------
// 256x128 ping-pong mainloop: 8 waves 4Mx2N, acc[4][4]. Frags for slab j+1
// read during slab j's 16 MFMA. Stage depth 3 (slab j+3 staged at iter j,
// slot j%3; 3 GLL/slab). Gate vmcnt(3)+lgkmcnt(0)+barrier.
// RSUM (fallback path): accumulate per-lane partial row sums of A frags.
// Swizzle: 16B-chunk ^= (row>>1)&3 on read; source pre-swizzled.
// ---------------------------------------------------------------------------
template <int K, bool RSUM>
__device__ __forceinline__ void gemm128_pp(
    const u16* __restrict__ A0, const u16* __restrict__ B0,
    u16* lds, f32x4 (&acc)[4][4], float* rs)
{
  const int tid = threadIdx.x;
  const int w = tid >> 6, l = tid & 63;
  const int wm = w >> 1, wn = w & 1;
  const int fr = l & 15;
  const int laneChunk = ((l >> 4) ^ ((fr >> 1) & 3)) << 3;
  const int laneA = (wm * 64 + fr) * 32 + laneChunk;
  const int laneB = (wn * 64 + fr) * 32 + laneChunk;
  u16* const ldsA = lds;                 // 3 slots x 8192 u16 (16 KB)
  u16* const ldsB = lds + 24576;         // 3 slots x 4096 u16 (8 KB)

  const int chunkS = ((tid & 3) ^ ((tid >> 3) & 3)) << 3;
  const int r0 = tid >> 2;               // 0..127
  const u16* const sA0 = A0 + (size_t)r0 * K + chunkS;
  const u16* const sA1 = A0 + (size_t)(r0 + 128) * K + chunkS;
  const u16* const sB0 = B0 + (size_t)r0 * K + chunkS;
  const int dOf = w * 512;

#define PSTAGE_A(j, slot) do {                                                 \
    u16* d_ = ldsA + (slot) * 8192 + dOf;                                      \
    GLL16(sA0 + (j) * 32, d_);                                                 \
    GLL16(sA1 + (j) * 32, d_ + 4096);                                          \
  } while (0)
#define PSTAGE_B(j, slot) do {                                                 \
    u16* d_ = ldsB + (slot) * 4096 + dOf;                                      \
    GLL16(sB0 + (j) * 32, d_);                                                 \
  } while (0)

  constexpr int NS = K / 32;
  bf16x8 aP[4], bP[4], aQ[4], bQ[4];     // statically-named ping-pong sets

  // prologue: stage slabs 0,1,2; wait slab 0 (vmcnt(6): newer = slabs 1,2);
  // pre-read frags[0] into P set
  PSTAGE_B(0, 0); PSTAGE_A(0, 0);
  PSTAGE_B(1, 1); PSTAGE_A(1, 1);
  PSTAGE_B(2, 2); PSTAGE_A(2, 2);
  asm volatile("s_waitcnt vmcnt(6)\n\ts_barrier" ::: "memory");
#pragma unroll
  for (int i = 0; i < 4; ++i) aP[i] = *(const bf16x8*)(ldsA + laneA + i * 512);
#pragma unroll
  for (int i = 0; i < 4; ++i) bP[i] = *(const bf16x8*)(ldsB + laneB + i * 512);

  // iter jj: MFMA on C-set (slab jj, read last iter); read N-set (slab jj+1)
  // from slot (jj+1)%3; stage slab jj+3 into slot jj%3 (post-barrier, safe:
  // all reads of that slot drained by this gate's lgkmcnt(0)).
#define KITER(jj, CA, CB, NA, NB) do {                                         \
    const int js_ = ((jj) + 3 < NS) ? (jj) + 3 : NS - 1;                       \
    const int sS_ = (jj) % 3;                                                  \
    const int sR_ = ((jj) + 1) % 3;                                            \
    asm volatile("s_waitcnt vmcnt(3) lgkmcnt(0)\n\ts_barrier" ::: "memory");   \
    const u16* const Ab_ = ldsA + sR_ * 8192;                                  \
    const u16* const Bb_ = ldsB + sR_ * 4096;                                  \
    _Pragma("unroll")                                                          \
    for (int i = 0; i < 4; ++i) NB[i] = *(const bf16x8*)(Bb_ + laneB + i * 512); \
    _Pragma("unroll")                                                          \
    for (int i = 0; i < 4; ++i) NA[i] = *(const bf16x8*)(Ab_ + laneA + i * 512); \
    PSTAGE_B(js_, sS_);                                                        \
    __builtin_amdgcn_s_setprio(1);                                             \
    _Pragma("unroll")                                                          \
    for (int mi = 0; mi < 2; ++mi)                                             \
      _Pragma("unroll")                                                        \
      for (int nj = 0; nj < 4; ++nj)                                           \
        acc[mi][nj] = __builtin_amdgcn_mfma_f32_16x16x32_bf16(                 \
            CA[mi], CB[nj], acc[mi][nj], 0, 0, 0);                             \
    __builtin_amdgcn_s_setprio(0);                                             \
    PSTAGE_A(js_, sS_);                                                        \
    __builtin_amdgcn_s_setprio(1);                                             \
    _Pragma("unroll")                                                          \
    for (int mi = 2; mi < 4; ++mi)                                             \
      _Pragma("unroll")                                                        \
      for (int nj = 0; nj < 4; ++nj)                                           \
        acc[mi][nj] = __builtin_amdgcn_mfma_f32_16x16x32_bf16(                 \
            CA[mi], CB[nj], acc[mi][nj], 0, 0, 0);                             \
    __builtin_amdgcn_s_setprio(0);                                             \
    if (RSUM) {                                                                \
      _Pragma("unroll")                                                        \
      for (int i = 0; i < 4; ++i) {                                            \
        float s_ = 0.f;                                                        \
        _Pragma("unroll")                                                      \
        for (int e = 0; e < 8; ++e) s_ += bf2f((u16)CA[i][e]);                 \
        rs[i] += s_;                                                           \
      }                                                                        \
    }                                                                          \
  } while (0)

  for (int j = 0; j < NS; j += 2) {      // NS even (16/64); static reg names
    KITER(j, aP, bP, aQ, bQ);
    KITER(j + 1, aQ, bQ, aP, bP);
  }
#undef KITER
#undef PSTAGE_A
#undef PSTAGE_B
}

// ---------------------------------------------------------------------------
// 256x256 ping-pong mainloop (scores) - R13, proven.
// ---------------------------------------------------------------------------
template <int K>
__device__ __forceinline__ void gemm8p_256sq_pp(
    const u16* __restrict__ A0, const u16* __restrict__ B0,
    u16* lds, f32x4 (&acc)[8][4])
{
  const int tid = threadIdx.x;
  const int w = tid >> 6, l = tid & 63;
  const int wm = w >> 2, wn = w & 3;
  const int fr = l & 15;
  const int laneChunk = ((l >> 4) ^ ((fr >> 1) & 3)) << 3;
  const int laneA = (wm * 128 + fr) * 32 + laneChunk;
  const int laneB = (wn * 64 + fr) * 32 + laneChunk;
  u16* const ldsA = lds;                 // 3 slots x 8192 u16 (16 KB)
  u16* const ldsB = lds + 24576;         // 3 slots x 8192 u16 (16 KB)

  const int chunkS = ((tid & 3) ^ ((tid >> 3) & 3)) << 3;
  const int r0 = tid >> 2;               // 0..127
  const u16* const sA0 = A0 + (size_t)r0 * K + chunkS;
  const u16* const sA1 = A0 + (size_t)(r0 + 128) * K + chunkS;
  const u16* const sB0 = B0 + (size_t)r0 * K + chunkS;
  const u16* const sB1 = B0 + (size_t)(r0 + 128) * K + chunkS;
  const int dOf = w * 512;

#define SSTAGE_A(j, slot) do {                                                 \
    u16* d_ = ldsA + (slot) * 8192 + dOf;                                      \
    GLL16(sA0 + (j) * 32, d_);                                                 \
    GLL16(sA1 + (j) * 32, d_ + 4096);                                          \
  } while (0)
#define SSTAGE_B(j, slot) do {                                                 \
    u16* d_ = ldsB + (slot) * 8192 + dOf;                                      \
    GLL16(sB0 + (j) * 32, d_);                                                 \
    GLL16(sB1 + (j) * 32, d_ + 4096);                                          \
  } while (0)

  constexpr int NS = K / 32;
  bf16x8 bP[4], aP0[4], aP1[4], bQ[4], aQ0[4], aQ1[4];

  SSTAGE_B(0, 0); SSTAGE_A(0, 0);
  SSTAGE_B(1, 1); SSTAGE_A(1, 1);
  SSTAGE_B(2, 2); SSTAGE_A(2, 2);
  asm volatile("s_waitcnt vmcnt(8)\n\ts_barrier" ::: "memory");
#pragma unroll
  for (int i = 0; i < 4; ++i) bP[i]  = *(const bf16x8*)(ldsB + laneB + i * 512);
#pragma unroll
  for (int i = 0; i < 4; ++i) aP0[i] = *(const bf16x8*)(ldsA + laneA + i * 512);
#pragma unroll
  for (int i = 0; i < 4; ++i) aP1[i] = *(const bf16x8*)(ldsA + laneA + (4 + i) * 512);

#define SITER(jj, CB, CA0, CA1, NB, NA0, NA1) do {                             \
    const int js_ = ((jj) + 3 < NS) ? (jj) + 3 : NS - 1;                       \
    const int sS_ = (jj) % 3;                                                  \
    const int sR_ = ((jj) + 1) % 3;                                            \
    asm volatile("s_waitcnt vmcnt(4) lgkmcnt(0)\n\ts_barrier" ::: "memory");   \
    const u16* const Ab_ = ldsA + sR_ * 8192;                                  \
    const u16* const Bb_ = ldsB + sR_ * 8192;                                  \
    _Pragma("unroll")                                                          \
    for (int i = 0; i < 4; ++i) NB[i]  = *(const bf16x8*)(Bb_ + laneB + i * 512); \
    _Pragma("unroll")                                                          \
    for (int i = 0; i < 4; ++i) NA0[i] = *(const bf16x8*)(Ab_ + laneA + i * 512); \
    SSTAGE_A(js_, sS_);                                                        \
    __builtin_amdgcn_s_setprio(1);                                             \
    _Pragma("unroll")                                                          \
    for (int mi = 0; mi < 4; ++mi)                                             \
      _Pragma("unroll")                                                        \
      for (int nj = 0; nj < 4; ++nj)                                           \
        acc[mi][nj] = __builtin_amdgcn_mfma_f32_16x16x32_bf16(                 \
            CA0[mi], CB[nj], acc[mi][nj], 0, 0, 0);                            \
    __builtin_amdgcn_s_setprio(0);                                             \
    _Pragma("unroll")                                                          \
    for (int i = 0; i < 4; ++i) NA1[i] = *(const bf16x8*)(Ab_ + laneA + (4 + i) * 512); \
    SSTAGE_B(js_, sS_);                                                        \
    __builtin_amdgcn_s_setprio(1);                                             \
    _Pragma("unroll")                                                          \
    for (int mi = 0; mi < 4; ++mi)                                             \
      _Pragma("unroll")                                                        \
      for (int nj = 0; nj < 4; ++nj)                                           \
        acc[4 + mi][nj] = __builtin_amdgcn_mfma_f32_16x16x32_bf16(             \
            CA1[mi], CB[nj], acc[4 + mi][nj], 0, 0, 0);                        \
    __builtin_amdgcn_s_setprio(0);                                             \
  } while (0)

  for (int j = 0; j < NS; j += 2) {
    SITER(j, bP, aP0, aP1, bQ, aQ0, aQ1);
    SITER(j + 1, bQ, aQ0, aQ1, bP, aP0, aP1);
  }
#undef SITER
#undef SSTAGE_A
#undef SSTAGE_B
}

// ---------------------------------------------------------------------------
// Kernels
// ---------------------------------------------------------------------------

__global__ void convert_x_kernel(const float* __restrict__ x, u16* __restrict__ xb,
                                 float* __restrict__ rsum) {
  int i = blockIdx.x * 256 + threadIdx.x;       // 2,097,152 threads * 4 floats
  float4 f = ((const float4*)x)[i];
  u16x4 o = { f2bf(f.x), f2bf(f.y), f2bf(f.z), f2bf(f.w) };
  ((u16x4*)xb)[i] = o;
  if (rsum != nullptr && blockIdx.x < 64)       // zero rsum[8][2048]
    rsum[blockIdx.x * 256 + threadIdx.x] = 0.f;
}

// W[m][d][e] f32 -> Wt[m][e][d] bf16 (LDS-tiled transpose)
__global__ void convw_kernel(const float* __restrict__ W, u16* __restrict__ wT) {
  __shared__ float tile[32][33];
  const int mtx = blockIdx.z;
  const int e0 = blockIdx.x * 32, d0 = blockIdx.y * 32;
  const int tx = threadIdx.x, ty = threadIdx.y;
  const float* Wm = W + (size_t)mtx * 262144;
#pragma unroll
  for (int i = 0; i < 32; i += 8)
    tile[ty + i][tx] = Wm[(size_t)(d0 + ty + i) * 512 + e0 + tx];
  __syncthreads();
  u16* T = wT + (size_t)mtx * 262144;
#pragma unroll
  for (int i = 0; i < 32; i += 8)
    T[(size_t)(e0 + ty + i) * 512 + d0 + tx] = f2bf(tile[tx][ty + i]);
}

// QKV: xb[16384,512] . wT[1536,512]^T via 256x128 ping-pong tiles.
// Swizzle: xcd = id&7 owns batch xcd's m-rows: x 2MB + wT 1.5MB L2-resident.
__global__ __launch_bounds__(512, 4) void gemm_qkv128_kernel(
    const u16* __restrict__ xb, const u16* __restrict__ wT,
    u16* __restrict__ qb, u16* __restrict__ kb, u16* __restrict__ vt)
{
  __shared__ __align__(16) u16 lds[36864];   // 72 KB
  const int id = blockIdx.x;                 // 768 blocks
  const int xcd = id & 7, t = id >> 3;       // t: 0..95
  const int n0 = (t % 12) * 128;
  const int m0 = (xcd * 8 + t / 12) * 256;
  f32x4 acc[4][4] = {};
  gemm128_pp<512, false>(xb + (size_t)m0 * 512, wT + (size_t)n0 * 512, lds, acc, nullptr);

  const int tid = threadIdx.x, w = tid >> 6, l = tid & 63;
  const int wm = w >> 1, wn = w & 1;
  const int which = n0 >> 9;                 // 0=q 1=k 2=v
  const int eb = (n0 & 511) + wn * 64 + (l & 15);
  const int rb = m0 + wm * 64 + (l >> 4) * 4;
  if (which < 2) {
    u16* dst = which ? kb : qb;
#pragma unroll
    for (int mi = 0; mi < 4; ++mi)
#pragma unroll
      for (int nj = 0; nj < 4; ++nj) {
        const int row = rb + mi * 16;
        const int col = eb + nj * 16;
#pragma unroll
        for (int r = 0; r < 4; ++r)
          dst[(size_t)(row + r) * 512 + col] = f2bf(acc[mi][nj][r]);
      }
  } else {
#pragma unroll
    for (int mi = 0; mi < 4; ++mi)
#pragma unroll
      for (int nj = 0; nj < 4; ++nj) {
        const int s = rb + mi * 16;            // global row (b*2048+s)
        const int b = s >> 11, sl = s & 2047;
        const int e = eb + nj * 16;
        u16x4 pk;
#pragma unroll
        for (int r = 0; r < 4; ++r) pk[r] = f2bf(acc[mi][nj][r]);
        *(u16x4*)(vt + (size_t)b * 1048576 + (size_t)e * 2048 + sl) = pk;
      }
  }
}

// P[z] = exp(Q[z].K[z]^T * 0.125) -> bf16 (unnormalized). If rsum != null,
// also atomicAdd per-row sums of the f32 exp values into rsum[z][row].
// 256x256 ping-pong tiles; 512 blocks = 2 rounds at 1 blk/CU; z = id&7.
__global__ __launch_bounds__(512, 2) void gemm_scores256_kernel(
    const u16* __restrict__ qb, const u16* __restrict__ kb,
    u16* __restrict__ attn, float* __restrict__ rsum)
{
  __shared__ __align__(16) u16 lds[49152];   // 96 KB
  const int id = blockIdx.x;                 // 512 blocks
  const int z = id & 7, t = id >> 3;         // t: 0..63
  const int n0 = (t & 7) * 256;
  const int m0 = (t >> 3) * 256;
  f32x4 acc[8][4] = {};
  gemm8p_256sq_pp<512>(qb + (size_t)z * 1048576 + (size_t)m0 * 512,
                       kb + (size_t)z * 1048576 + (size_t)n0 * 512, lds, acc);

  const int tid = threadIdx.x, w = tid >> 6, l = tid & 63;
  const int wm = w >> 2, wn = w & 3;
  u16* C = attn + (size_t)z * 4194304;
  const int rb = m0 + wm * 128 + (l >> 4) * 4;
  const int cb = n0 + wn * 64 + (l & 15);
  float rp[8][4];
#pragma unroll
  for (int mi = 0; mi < 8; ++mi)
#pragma unroll
    for (int r = 0; r < 4; ++r) rp[mi][r] = 0.f;

#pragma unroll
  for (int mi = 0; mi < 8; ++mi)
#pragma unroll
    for (int nj = 0; nj < 4; ++nj) {
      const int row = rb + mi * 16;
      const int col = cb + nj * 16;
#pragma unroll
      for (int r = 0; r < 4; ++r) {
        const float e = __expf(acc[mi][nj][r] * 0.125f);
        C[(size_t)(row + r) * 2048 + col] = f2bf(e);
        rp[mi][r] += e;
      }
    }

  if (rsum != nullptr) {
    float* rz = rsum + (size_t)z * 2048;
#pragma unroll
    for (int mi = 0; mi < 8; ++mi)
#pragma unroll
      for (int r = 0; r < 4; ++r) {
        float v = rp[mi][r];                   // reduce 16 col-lanes (l&15)
        v += __shfl_xor(v, 1);
        v += __shfl_xor(v, 2);
        v += __shfl_xor(v, 4);
        v += __shfl_xor(v, 8);
        if ((l & 15) == 0) atomicAdd(&rz[rb + mi * 16 + r], v);
      }
  }
}

// out[z] = (P[z].V[z]) / rowsum. FAST: rowsum read from rsum (scores-side
// atomics). Fallback: rowsum accumulated from A-frags in the mainloop.
template <bool FAST>
__global__ __launch_bounds__(512, 4) void gemm_pv8p_kernel(
    const u16* __restrict__ attn, const u16* __restrict__ vt,
    const float* __restrict__ rsum, float* __restrict__ out)
{
  __shared__ __align__(16) u16 lds[36864];   // 72 KB
  __shared__ float rowsumLDS[256];
  const int id = blockIdx.x;                 // 256 blocks
  const int z = id & 7;                      // id%8 = XCD (T1): one z per XCD
  const int j = id >> 3;                     // 0..31
  const int n0 = (j & 3) * 128;              // 4 n-tiles
  const int m0 = (j >> 2) * 256;             // 8 m-tiles
  f32x4 acc[4][4] = {};
  float rs[4] = {0.f, 0.f, 0.f, 0.f};
  gemm128_pp<2048, !FAST>(attn + (size_t)z * 4194304 + (size_t)m0 * 2048,
                          vt + (size_t)z * 1048576 + (size_t)n0 * 2048, lds, acc, rs);

  const int tid = threadIdx.x, w = tid >> 6, l = tid & 63;
  const int wm = w >> 1, wn = w & 1;
  const int rb = m0 + wm * 64 + (l >> 4) * 4;
  const int cb = n0 + wn * 64 + (l & 15);
  float* C = out + (size_t)z * 1048576;

  if (FAST) {
    const float* rz = rsum + (size_t)z * 2048;
#pragma unroll
    for (int mi = 0; mi < 4; ++mi)
#pragma unroll
      for (int r = 0; r < 4; ++r) {
        const float inv = 1.f / rz[rb + mi * 16 + r];
        const int row = rb + mi * 16 + r;
#pragma unroll
        for (int nj = 0; nj < 4; ++nj)
          C[(size_t)row * 512 + cb + nj * 16] = acc[mi][nj][r] * inv;
      }
  } else {
    __syncthreads();                         // mainloop LDS fully consumed
#pragma unroll
    for (int mi = 0; mi < 4; ++mi) {
      rs[mi] += __shfl_xor(rs[mi], 16);
      rs[mi] += __shfl_xor(rs[mi], 32);
    }
    if ((l >> 4) == 0) {
#pragma unroll
      for (int mi = 0; mi < 4; ++mi)
        rowsumLDS[wm * 64 + mi * 16 + l] = rs[mi];
    }
    __syncthreads();
#pragma unroll
    for (int mi = 0; mi < 4; ++mi)
#pragma unroll
      for (int r = 0; r < 4; ++r) {
        const float inv = 1.f / rowsumLDS[wm * 64 + mi * 16 + (l >> 4) * 4 + r];
        const int row = rb + mi * 16 + r;
#pragma unroll
        for (int nj = 0; nj < 4; ++nj)
          C[(size_t)row * 512 + cb + nj * 16] = acc[mi][nj][r] * inv;
      }
  }
}

// ---------------------------------------------------------------------------
extern "C" void kernel_launch(void* const* d_in, const int* in_sizes, int n_in,
                              void* d_out, int out_size, void* d_ws, size_t ws_size,
                              hipStream_t stream) {
  const float* x = (const float*)d_in[0];   // [8,2048,512]
  const float* W = (const float*)d_in[1];   // [3,512,512]
  float* out = (float*)d_out;               // [8,2048,512]

  if (ws_size < 117440512) return;          // 112 MiB minimum
  u16* wsu  = (u16*)d_ws;
  u16* qb   = wsu;
  u16* kb   = qb + 8388608;
  u16* vt   = kb + 8388608;
  u16* attn = vt + 8388608;
  u16* xb   = attn;                         // alias: dead before scores written
  u16* wT   = attn + 8388608;               // alias: dead before scores written

  const bool fast = ws_size >= 117440512 + 65536;   // room for rsum[8][2048] f32
  float* rsum = fast ? (float*)(wsu + 58720256) : nullptr;

  convert_x_kernel<<<8192, 256, 0, stream>>>(x, xb, rsum);
  convw_kernel<<<dim3(16, 16, 3), dim3(32, 8), 0, stream>>>(W, wT);
  gemm_qkv128_kernel<<<768, 512, 0, stream>>>(xb, wT, qb, kb, vt);
  gemm_scores256_kernel<<<512, 512, 0, stream>>>(qb, kb, attn, rsum);
  if (fast)
    gemm_pv8p_kernel<true><<<256, 512, 0, stream>>>(attn, vt, rsum, out);
  else
    gemm_pv8p_kernel<false><<<256, 512, 0, stream>>>(attn, vt, nullptr, out);
}

// Round 15
// 138.341 us; speedup vs baseline: 1.9739x; 1.9739x over previous
//
#include <hip/hip_runtime.h>

// SelfAttention: x[8,2048,512] f32, W[3,512,512] f32 -> out[8,2048,512] f32
// scale = 1/sqrt(64) = 0.125
//
// R15: R14's gemm128_pp spilled (acc 64 + pingpong frags 64 + addr > 128
// VGPR cap at bounds(512,4): WRITE_SIZE 50->204MB, MfmaUtil 0.4%). RULE:
// frag ping-pong only fits 1-blk/CU kernels (256 VGPR budget) - scores 256sq
// keeps it (bounds(512,2), proven R13); qkv/pv revert to the single-set
// 256x128 loop (bounds(512,4), VGPR ~64). Kept from R14: rsum computed in
// scores' epilogue (shfl + atomicAdd, buffer in ws tail zeroed by convert_x);
// pv normalizes from rsum in its epilogue (no in-loop VALU) with R13
// in-loop fallback if ws lacks the 64KB tail.

typedef unsigned short u16;
typedef unsigned int u32;

using bf16x8 = __attribute__((ext_vector_type(8))) short;   // 8 bf16 (4 VGPRs)
using f32x4  = __attribute__((ext_vector_type(4))) float;
using u16x4  = __attribute__((ext_vector_type(4))) u16;

__device__ __forceinline__ u16 f2bf(float f) {
  u32 u = __float_as_uint(f);
  u32 r = (u + 0x7FFFu + ((u >> 16) & 1u)) >> 16;   // RNE
  return (u16)r;
}
__device__ __forceinline__ float bf2f(u16 h) {
  return __uint_as_float(((u32)h) << 16);
}

#define GLL16(src, dst)                                                        \
  __builtin_amdgcn_global_load_lds(                                            \
      (const __attribute__((address_space(1))) void*)(src),                    \
      (__attribute__((address_space(3))) void*)(dst), 16, 0, 0)

// ---------------------------------------------------------------------------
// 256x128 mainloop (R10/R13, proven, single frag set): 8 waves 4Mx2N,
// acc[4][4], 3-slot BK=32, gate vmcnt(3)+barrier, one barrier per slab.
// RSUM (fallback): accumulate per-lane partial row sums of A frags.
// ---------------------------------------------------------------------------
template <int K, bool RSUM>
__device__ __forceinline__ void gemm8p_256x128(
    const u16* __restrict__ A0, const u16* __restrict__ B0,
    u16* lds, f32x4 (&acc)[4][4], float* rs)
{
  const int tid = threadIdx.x;
  const int w = tid >> 6, l = tid & 63;
  const int wm = w >> 1, wn = w & 1;
  const int fr = l & 15;
  const int laneChunk = ((l >> 4) ^ ((fr >> 1) & 3)) << 3;
  const int laneA = (wm * 64 + fr) * 32 + laneChunk;
  const int laneB = (wn * 64 + fr) * 32 + laneChunk;
  u16* const ldsA = lds;                 // 3 slots x 8192 u16 (16 KB)
  u16* const ldsB = lds + 24576;         // 3 slots x 4096 u16 (8 KB)

  const int chunkS = ((tid & 3) ^ ((tid >> 3) & 3)) << 3;
  const int r0 = tid >> 2;               // 0..127
  const u16* const sA0 = A0 + (size_t)r0 * K + chunkS;
  const u16* const sA1 = A0 + (size_t)(r0 + 128) * K + chunkS;
  const u16* const sB0 = B0 + (size_t)r0 * K + chunkS;
  const int dOf = w * 512;

#define PSTAGE_A(j, slot) do {                                                 \
    u16* d_ = ldsA + (slot) * 8192 + dOf;                                      \
    GLL16(sA0 + (j) * 32, d_);                                                 \
    GLL16(sA1 + (j) * 32, d_ + 4096);                                          \
  } while (0)
#define PSTAGE_B(j, slot) do {                                                 \
    u16* d_ = ldsB + (slot) * 4096 + dOf;                                      \
    GLL16(sB0 + (j) * 32, d_);                                                 \
  } while (0)

  PSTAGE_B(0, 0); PSTAGE_A(0, 0);
  PSTAGE_B(1, 1); PSTAGE_A(1, 1);

  constexpr int NS = K / 32;
  int slot = 0;
  for (int j = 0; j < NS; ++j) {
    const int jn = (j + 2 < NS) ? (j + 2) : (NS - 1);   // clamped (dups land
    int slotn = slot + 2; if (slotn >= 3) slotn -= 3;   //  in dead slot)

    asm volatile("s_waitcnt vmcnt(3)\n\ts_barrier" ::: "memory");

    const u16* const Ab = ldsA + slot * 8192;
    const u16* const Bb = ldsB + slot * 4096;
    bf16x8 a[4], b[4];
#pragma unroll
    for (int i = 0; i < 4; ++i) a[i] = *(const bf16x8*)(Ab + laneA + i * 512);
#pragma unroll
    for (int i = 0; i < 4; ++i) b[i] = *(const bf16x8*)(Bb + laneB + i * 512);
    PSTAGE_B(jn, slotn);
    __builtin_amdgcn_s_setprio(1);
#pragma unroll
    for (int mi = 0; mi < 2; ++mi)
#pragma unroll
      for (int nj = 0; nj < 4; ++nj)
        acc[mi][nj] = __builtin_amdgcn_mfma_f32_16x16x32_bf16(a[mi], b[nj], acc[mi][nj], 0, 0, 0);
    __builtin_amdgcn_s_setprio(0);
    PSTAGE_A(jn, slotn);
    __builtin_amdgcn_s_setprio(1);
#pragma unroll
    for (int mi = 2; mi < 4; ++mi)
#pragma unroll
      for (int nj = 0; nj < 4; ++nj)
        acc[mi][nj] = __builtin_amdgcn_mfma_f32_16x16x32_bf16(a[mi], b[nj], acc[mi][nj], 0, 0, 0);
    __builtin_amdgcn_s_setprio(0);

    if (RSUM) {
#pragma unroll
      for (int i = 0; i < 4; ++i) {
        float s_ = 0.f;
#pragma unroll
        for (int e = 0; e < 8; ++e) s_ += bf2f((u16)a[i][e]);
        rs[i] += s_;
      }
    }

    slot = (slot == 2) ? 0 : slot + 1;
  }
#undef PSTAGE_A
#undef PSTAGE_B
}

// ---------------------------------------------------------------------------
// 256x256 ping-pong mainloop (scores) - R13, proven. bounds(512,2): the
// 6 frag sets + acc[8][4] fit the 256-VGPR budget (1 blk/CU).
// ---------------------------------------------------------------------------
template <int K>
__device__ __forceinline__ void gemm8p_256sq_pp(
    const u16* __restrict__ A0, const u16* __restrict__ B0,
    u16* lds, f32x4 (&acc)[8][4])
{
  const int tid = threadIdx.x;
  const int w = tid >> 6, l = tid & 63;
  const int wm = w >> 2, wn = w & 3;
  const int fr = l & 15;
  const int laneChunk = ((l >> 4) ^ ((fr >> 1) & 3)) << 3;
  const int laneA = (wm * 128 + fr) * 32 + laneChunk;
  const int laneB = (wn * 64 + fr) * 32 + laneChunk;
  u16* const ldsA = lds;                 // 3 slots x 8192 u16 (16 KB)
  u16* const ldsB = lds + 24576;         // 3 slots x 8192 u16 (16 KB)

  const int chunkS = ((tid & 3) ^ ((tid >> 3) & 3)) << 3;
  const int r0 = tid >> 2;               // 0..127
  const u16* const sA0 = A0 + (size_t)r0 * K + chunkS;
  const u16* const sA1 = A0 + (size_t)(r0 + 128) * K + chunkS;
  const u16* const sB0 = B0 + (size_t)r0 * K + chunkS;
  const u16* const sB1 = B0 + (size_t)(r0 + 128) * K + chunkS;
  const int dOf = w * 512;

#define SSTAGE_A(j, slot) do {                                                 \
    u16* d_ = ldsA + (slot) * 8192 + dOf;                                      \
    GLL16(sA0 + (j) * 32, d_);                                                 \
    GLL16(sA1 + (j) * 32, d_ + 4096);                                          \
  } while (0)
#define SSTAGE_B(j, slot) do {                                                 \
    u16* d_ = ldsB + (slot) * 8192 + dOf;                                      \
    GLL16(sB0 + (j) * 32, d_);                                                 \
    GLL16(sB1 + (j) * 32, d_ + 4096);                                          \
  } while (0)

  constexpr int NS = K / 32;
  bf16x8 bP[4], aP0[4], aP1[4], bQ[4], aQ0[4], aQ1[4];

  SSTAGE_B(0, 0); SSTAGE_A(0, 0);
  SSTAGE_B(1, 1); SSTAGE_A(1, 1);
  SSTAGE_B(2, 2); SSTAGE_A(2, 2);
  asm volatile("s_waitcnt vmcnt(8)\n\ts_barrier" ::: "memory");
#pragma unroll
  for (int i = 0; i < 4; ++i) bP[i]  = *(const bf16x8*)(ldsB + laneB + i * 512);
#pragma unroll
  for (int i = 0; i < 4; ++i) aP0[i] = *(const bf16x8*)(ldsA + laneA + i * 512);
#pragma unroll
  for (int i = 0; i < 4; ++i) aP1[i] = *(const bf16x8*)(ldsA + laneA + (4 + i) * 512);

#define SITER(jj, CB, CA0, CA1, NB, NA0, NA1) do {                             \
    const int js_ = ((jj) + 3 < NS) ? (jj) + 3 : NS - 1;                       \
    const int sS_ = (jj) % 3;                                                  \
    const int sR_ = ((jj) + 1) % 3;                                            \
    asm volatile("s_waitcnt vmcnt(4) lgkmcnt(0)\n\ts_barrier" ::: "memory");   \
    const u16* const Ab_ = ldsA + sR_ * 8192;                                  \
    const u16* const Bb_ = ldsB + sR_ * 8192;                                  \
    _Pragma("unroll")                                                          \
    for (int i = 0; i < 4; ++i) NB[i]  = *(const bf16x8*)(Bb_ + laneB + i * 512); \
    _Pragma("unroll")                                                          \
    for (int i = 0; i < 4; ++i) NA0[i] = *(const bf16x8*)(Ab_ + laneA + i * 512); \
    SSTAGE_A(js_, sS_);                                                        \
    __builtin_amdgcn_s_setprio(1);                                             \
    _Pragma("unroll")                                                          \
    for (int mi = 0; mi < 4; ++mi)                                             \
      _Pragma("unroll")                                                        \
      for (int nj = 0; nj < 4; ++nj)                                           \
        acc[mi][nj] = __builtin_amdgcn_mfma_f32_16x16x32_bf16(                 \
            CA0[mi], CB[nj], acc[mi][nj], 0, 0, 0);                            \
    __builtin_amdgcn_s_setprio(0);                                             \
    _Pragma("unroll")                                                          \
    for (int i = 0; i < 4; ++i) NA1[i] = *(const bf16x8*)(Ab_ + laneA + (4 + i) * 512); \
    SSTAGE_B(js_, sS_);                                                        \
    __builtin_amdgcn_s_setprio(1);                                             \
    _Pragma("unroll")                                                          \
    for (int mi = 0; mi < 4; ++mi)                                             \
      _Pragma("unroll")                                                        \
      for (int nj = 0; nj < 4; ++nj)                                           \
        acc[4 + mi][nj] = __builtin_amdgcn_mfma_f32_16x16x32_bf16(             \
            CA1[mi], CB[nj], acc[4 + mi][nj], 0, 0, 0);                        \
    __builtin_amdgcn_s_setprio(0);                                             \
  } while (0)

  for (int j = 0; j < NS; j += 2) {
    SITER(j, bP, aP0, aP1, bQ, aQ0, aQ1);
    SITER(j + 1, bQ, aQ0, aQ1, bP, aP0, aP1);
  }
#undef SITER
#undef SSTAGE_A
#undef SSTAGE_B
}

// ---------------------------------------------------------------------------
// Kernels
// ---------------------------------------------------------------------------

__global__ void convert_x_kernel(const float* __restrict__ x, u16* __restrict__ xb,
                                 float* __restrict__ rsum) {
  int i = blockIdx.x * 256 + threadIdx.x;       // 2,097,152 threads * 4 floats
  float4 f = ((const float4*)x)[i];
  u16x4 o = { f2bf(f.x), f2bf(f.y), f2bf(f.z), f2bf(f.w) };
  ((u16x4*)xb)[i] = o;
  if (rsum != nullptr && blockIdx.x < 64)       // zero rsum[8][2048]
    rsum[blockIdx.x * 256 + threadIdx.x] = 0.f;
}

// W[m][d][e] f32 -> Wt[m][e][d] bf16 (LDS-tiled transpose)
__global__ void convw_kernel(const float* __restrict__ W, u16* __restrict__ wT) {
  __shared__ float tile[32][33];
  const int mtx = blockIdx.z;
  const int e0 = blockIdx.x * 32, d0 = blockIdx.y * 32;
  const int tx = threadIdx.x, ty = threadIdx.y;
  const float* Wm = W + (size_t)mtx * 262144;
#pragma unroll
  for (int i = 0; i < 32; i += 8)
    tile[ty + i][tx] = Wm[(size_t)(d0 + ty + i) * 512 + e0 + tx];
  __syncthreads();
  u16* T = wT + (size_t)mtx * 262144;
#pragma unroll
  for (int i = 0; i < 32; i += 8)
    T[(size_t)(e0 + ty + i) * 512 + d0 + tx] = f2bf(tile[tx][ty + i]);
}

// QKV: xb[16384,512] . wT[1536,512]^T via 256x128 tiles (single frag set).
// Swizzle: xcd = id&7 owns batch xcd's m-rows: x 2MB + wT 1.5MB L2-resident.
__global__ __launch_bounds__(512, 4) void gemm_qkv128_kernel(
    const u16* __restrict__ xb, const u16* __restrict__ wT,
    u16* __restrict__ qb, u16* __restrict__ kb, u16* __restrict__ vt)
{
  __shared__ __align__(16) u16 lds[36864];   // 72 KB
  const int id = blockIdx.x;                 // 768 blocks
  const int xcd = id & 7, t = id >> 3;       // t: 0..95
  const int n0 = (t % 12) * 128;
  const int m0 = (xcd * 8 + t / 12) * 256;
  f32x4 acc[4][4] = {};
  gemm8p_256x128<512, false>(xb + (size_t)m0 * 512, wT + (size_t)n0 * 512, lds, acc, nullptr);

  const int tid = threadIdx.x, w = tid >> 6, l = tid & 63;
  const int wm = w >> 1, wn = w & 1;
  const int which = n0 >> 9;                 // 0=q 1=k 2=v
  const int eb = (n0 & 511) + wn * 64 + (l & 15);
  const int rb = m0 + wm * 64 + (l >> 4) * 4;
  if (which < 2) {
    u16* dst = which ? kb : qb;
#pragma unroll
    for (int mi = 0; mi < 4; ++mi)
#pragma unroll
      for (int nj = 0; nj < 4; ++nj) {
        const int row = rb + mi * 16;
        const int col = eb + nj * 16;
#pragma unroll
        for (int r = 0; r < 4; ++r)
          dst[(size_t)(row + r) * 512 + col] = f2bf(acc[mi][nj][r]);
      }
  } else {
#pragma unroll
    for (int mi = 0; mi < 4; ++mi)
#pragma unroll
      for (int nj = 0; nj < 4; ++nj) {
        const int s = rb + mi * 16;            // global row (b*2048+s)
        const int b = s >> 11, sl = s & 2047;
        const int e = eb + nj * 16;
        u16x4 pk;
#pragma unroll
        for (int r = 0; r < 4; ++r) pk[r] = f2bf(acc[mi][nj][r]);
        *(u16x4*)(vt + (size_t)b * 1048576 + (size_t)e * 2048 + sl) = pk;
      }
  }
}

// P[z] = exp(Q[z].K[z]^T * 0.125) -> bf16 (unnormalized). If rsum != null,
// atomicAdd per-row sums of the f32 exp values into rsum[z][row].
// 256x256 ping-pong tiles; 512 blocks = 2 rounds at 1 blk/CU; z = id&7.
__global__ __launch_bounds__(512, 2) void gemm_scores256_kernel(
    const u16* __restrict__ qb, const u16* __restrict__ kb,
    u16* __restrict__ attn, float* __restrict__ rsum)
{
  __shared__ __align__(16) u16 lds[49152];   // 96 KB
  const int id = blockIdx.x;                 // 512 blocks
  const int z = id & 7, t = id >> 3;         // t: 0..63
  const int n0 = (t & 7) * 256;
  const int m0 = (t >> 3) * 256;
  f32x4 acc[8][4] = {};
  gemm8p_256sq_pp<512>(qb + (size_t)z * 1048576 + (size_t)m0 * 512,
                       kb + (size_t)z * 1048576 + (size_t)n0 * 512, lds, acc);

  const int tid = threadIdx.x, w = tid >> 6, l = tid & 63;
  const int wm = w >> 2, wn = w & 3;
  u16* C = attn + (size_t)z * 4194304;
  const int rb = m0 + wm * 128 + (l >> 4) * 4;
  const int cb = n0 + wn * 64 + (l & 15);

#pragma unroll
  for (int mi = 0; mi < 8; ++mi) {
    float rp[4] = {0.f, 0.f, 0.f, 0.f};
#pragma unroll
    for (int nj = 0; nj < 4; ++nj) {
      const int row = rb + mi * 16;
      const int col = cb + nj * 16;
#pragma unroll
      for (int r = 0; r < 4; ++r) {
        const float e = __expf(acc[mi][nj][r] * 0.125f);
        C[(size_t)(row + r) * 2048 + col] = f2bf(e);
        rp[r] += e;
      }
    }
    if (rsum != nullptr) {
      float* rz = rsum + (size_t)z * 2048;
#pragma unroll
      for (int r = 0; r < 4; ++r) {
        float v = rp[r];                       // reduce 16 col-lanes (l&15)
        v += __shfl_xor(v, 1);
        v += __shfl_xor(v, 2);
        v += __shfl_xor(v, 4);
        v += __shfl_xor(v, 8);
        if ((l & 15) == 0) atomicAdd(&rz[rb + mi * 16 + r], v);
      }
    }
  }
}

// out[z] = (P[z].V[z]) / rowsum. FAST: rowsum read from rsum (scores-side
// atomics) in the epilogue. Fallback: in-loop A-frag accumulation (R13).
template <bool FAST>
__global__ __launch_bounds__(512, 4) void gemm_pv8p_kernel(
    const u16* __restrict__ attn, const u16* __restrict__ vt,
    const float* __restrict__ rsum, float* __restrict__ out)
{
  __shared__ __align__(16) u16 lds[36864];   // 72 KB
  __shared__ float rowsumLDS[256];
  const int id = blockIdx.x;                 // 256 blocks
  const int z = id & 7;                      // id%8 = XCD (T1): one z per XCD
  const int j = id >> 3;                     // 0..31
  const int n0 = (j & 3) * 128;              // 4 n-tiles
  const int m0 = (j >> 2) * 256;             // 8 m-tiles
  f32x4 acc[4][4] = {};
  float rs[4] = {0.f, 0.f, 0.f, 0.f};
  gemm8p_256x128<2048, !FAST>(attn + (size_t)z * 4194304 + (size_t)m0 * 2048,
                              vt + (size_t)z * 1048576 + (size_t)n0 * 2048, lds, acc, rs);

  const int tid = threadIdx.x, w = tid >> 6, l = tid & 63;
  const int wm = w >> 1, wn = w & 1;
  const int rb = m0 + wm * 64 + (l >> 4) * 4;
  const int cb = n0 + wn * 64 + (l & 15);
  float* C = out + (size_t)z * 1048576;

  if (FAST) {
    const float* rz = rsum + (size_t)z * 2048;
#pragma unroll
    for (int mi = 0; mi < 4; ++mi)
#pragma unroll
      for (int r = 0; r < 4; ++r) {
        const float inv = 1.f / rz[rb + mi * 16 + r];
        const int row = rb + mi * 16 + r;
#pragma unroll
        for (int nj = 0; nj < 4; ++nj)
          C[(size_t)row * 512 + cb + nj * 16] = acc[mi][nj][r] * inv;
      }
  } else {
    __syncthreads();                         // mainloop LDS fully consumed
#pragma unroll
    for (int mi = 0; mi < 4; ++mi) {
      rs[mi] += __shfl_xor(rs[mi], 16);
      rs[mi] += __shfl_xor(rs[mi], 32);
    }
    if ((l >> 4) == 0) {
#pragma unroll
      for (int mi = 0; mi < 4; ++mi)
        rowsumLDS[wm * 64 + mi * 16 + l] = rs[mi];
    }
    __syncthreads();
#pragma unroll
    for (int mi = 0; mi < 4; ++mi)
#pragma unroll
      for (int r = 0; r < 4; ++r) {
        const float inv = 1.f / rowsumLDS[wm * 64 + mi * 16 + (l >> 4) * 4 + r];
        const int row = rb + mi * 16 + r;
#pragma unroll
        for (int nj = 0; nj < 4; ++nj)
          C[(size_t)row * 512 + cb + nj * 16] = acc[mi][nj][r] * inv;
      }
  }
}

// ---------------------------------------------------------------------------
extern "C" void kernel_launch(void* const* d_in, const int* in_sizes, int n_in,
                              void* d_out, int out_size, void* d_ws, size_t ws_size,
                              hipStream_t stream) {
  const float* x = (const float*)d_in[0];   // [8,2048,512]
  const float* W = (const float*)d_in[1];   // [3,512,512]
  float* out = (float*)d_out;               // [8,2048,512]

  if (ws_size < 117440512) return;          // 112 MiB minimum
  u16* wsu  = (u16*)d_ws;
  u16* qb   = wsu;
  u16* kb   = qb + 8388608;
  u16* vt   = kb + 8388608;
  u16* attn = vt + 8388608;
  u16* xb   = attn;                         // alias: dead before scores written
  u16* wT   = attn + 8388608;               // alias: dead before scores written

  const bool fast = ws_size >= 117440512 + 65536;   // room for rsum[8][2048] f32
  float* rsum = fast ? (float*)(wsu + 58720256) : nullptr;

  convert_x_kernel<<<8192, 256, 0, stream>>>(x, xb, rsum);
  convw_kernel<<<dim3(16, 16, 3), dim3(32, 8), 0, stream>>>(W, wT);
  gemm_qkv128_kernel<<<768, 512, 0, stream>>>(xb, wT, qb, kb, vt);
  gemm_scores256_kernel<<<512, 512, 0, stream>>>(qb, kb, attn, rsum);
  if (fast)
    gemm_pv8p_kernel<true><<<256, 512, 0, stream>>>(attn, vt, rsum, out);
  else
    gemm_pv8p_kernel<false><<<256, 512, 0, stream>>>(attn, vt, nullptr, out);
}

// Round 16
// 135.137 us; speedup vs baseline: 2.0207x; 1.0237x over previous
//
#include <hip/hip_runtime.h>

// SelfAttention: x[8,2048,512] f32, W[3,512,512] f32 -> out[8,2048,512] f32
// scale = 1/sqrt(64) = 0.125
//
// R16: R15's scores-side rsum cost +21us to save 13.5 (reverted; scores =
// R13 exact). Rowsum now a standalone bandwidth kernel (attn is L3-hot:
// 67MB read ~9us). pv, freed of in-loop rsum VALU, takes the ping-pong
// mainloop at bounds(512,2) - legal there because pv's grid is 256 blocks
// = 1 blk/CU regardless (R14's spill was the 128-VGPR cap at bounds(,4);
// R13 proved pp correct+fast in the 256-VGPR regime).

typedef unsigned short u16;
typedef unsigned int u32;

using bf16x8 = __attribute__((ext_vector_type(8))) short;   // 8 bf16 (4 VGPRs)
using f32x4  = __attribute__((ext_vector_type(4))) float;
using u16x4  = __attribute__((ext_vector_type(4))) u16;

__device__ __forceinline__ u16 f2bf(float f) {
  u32 u = __float_as_uint(f);
  u32 r = (u + 0x7FFFu + ((u >> 16) & 1u)) >> 16;   // RNE
  return (u16)r;
}
__device__ __forceinline__ float bf2f(u16 h) {
  return __uint_as_float(((u32)h) << 16);
}

#define GLL16(src, dst)                                                        \
  __builtin_amdgcn_global_load_lds(                                            \
      (const __attribute__((address_space(1))) void*)(src),                    \
      (__attribute__((address_space(3))) void*)(dst), 16, 0, 0)

// ---------------------------------------------------------------------------
// 256x128 single-frag-set mainloop (R10, proven): 8 waves 4Mx2N, acc[4][4],
// 3-slot BK=32, gate vmcnt(3)+barrier. Fits bounds(512,4) (VGPR ~64).
// RSUM: in-loop row-sum fallback for pv when ws lacks the rsum tail.
// ---------------------------------------------------------------------------
template <int K, bool RSUM>
__device__ __forceinline__ void gemm8p_256x128(
    const u16* __restrict__ A0, const u16* __restrict__ B0,
    u16* lds, f32x4 (&acc)[4][4], float* rs)
{
  const int tid = threadIdx.x;
  const int w = tid >> 6, l = tid & 63;
  const int wm = w >> 1, wn = w & 1;
  const int fr = l & 15;
  const int laneChunk = ((l >> 4) ^ ((fr >> 1) & 3)) << 3;
  const int laneA = (wm * 64 + fr) * 32 + laneChunk;
  const int laneB = (wn * 64 + fr) * 32 + laneChunk;
  u16* const ldsA = lds;                 // 3 slots x 8192 u16 (16 KB)
  u16* const ldsB = lds + 24576;         // 3 slots x 4096 u16 (8 KB)

  const int chunkS = ((tid & 3) ^ ((tid >> 3) & 3)) << 3;
  const int r0 = tid >> 2;               // 0..127
  const u16* const sA0 = A0 + (size_t)r0 * K + chunkS;
  const u16* const sA1 = A0 + (size_t)(r0 + 128) * K + chunkS;
  const u16* const sB0 = B0 + (size_t)r0 * K + chunkS;
  const int dOf = w * 512;

#define PSTAGE_A(j, slot) do {                                                 \
    u16* d_ = ldsA + (slot) * 8192 + dOf;                                      \
    GLL16(sA0 + (j) * 32, d_);                                                 \
    GLL16(sA1 + (j) * 32, d_ + 4096);                                          \
  } while (0)
#define PSTAGE_B(j, slot) do {                                                 \
    u16* d_ = ldsB + (slot) * 4096 + dOf;                                      \
    GLL16(sB0 + (j) * 32, d_);                                                 \
  } while (0)

  PSTAGE_B(0, 0); PSTAGE_A(0, 0);
  PSTAGE_B(1, 1); PSTAGE_A(1, 1);

  constexpr int NS = K / 32;
  int slot = 0;
  for (int j = 0; j < NS; ++j) {
    const int jn = (j + 2 < NS) ? (j + 2) : (NS - 1);
    int slotn = slot + 2; if (slotn >= 3) slotn -= 3;

    asm volatile("s_waitcnt vmcnt(3)\n\ts_barrier" ::: "memory");

    const u16* const Ab = ldsA + slot * 8192;
    const u16* const Bb = ldsB + slot * 4096;
    bf16x8 a[4], b[4];
#pragma unroll
    for (int i = 0; i < 4; ++i) a[i] = *(const bf16x8*)(Ab + laneA + i * 512);
#pragma unroll
    for (int i = 0; i < 4; ++i) b[i] = *(const bf16x8*)(Bb + laneB + i * 512);
    PSTAGE_B(jn, slotn);
    __builtin_amdgcn_s_setprio(1);
#pragma unroll
    for (int mi = 0; mi < 2; ++mi)
#pragma unroll
      for (int nj = 0; nj < 4; ++nj)
        acc[mi][nj] = __builtin_amdgcn_mfma_f32_16x16x32_bf16(a[mi], b[nj], acc[mi][nj], 0, 0, 0);
    __builtin_amdgcn_s_setprio(0);
    PSTAGE_A(jn, slotn);
    __builtin_amdgcn_s_setprio(1);
#pragma unroll
    for (int mi = 2; mi < 4; ++mi)
#pragma unroll
      for (int nj = 0; nj < 4; ++nj)
        acc[mi][nj] = __builtin_amdgcn_mfma_f32_16x16x32_bf16(a[mi], b[nj], acc[mi][nj], 0, 0, 0);
    __builtin_amdgcn_s_setprio(0);

    if (RSUM) {
#pragma unroll
      for (int i = 0; i < 4; ++i) {
        float s_ = 0.f;
#pragma unroll
        for (int e = 0; e < 8; ++e) s_ += bf2f((u16)a[i][e]);
        rs[i] += s_;
      }
    }

    slot = (slot == 2) ? 0 : slot + 1;
  }
#undef PSTAGE_A
#undef PSTAGE_B
}

// ---------------------------------------------------------------------------
// 256x128 ping-pong mainloop (pv FAST): frags[j+1] read during MFMA[j];
// stage depth 3, gate vmcnt(3)+lgkmcnt(0). Needs 256-VGPR budget ->
// bounds(512,2) only; pv's 256-block grid is 1 blk/CU anyway (R14 lesson).
// ---------------------------------------------------------------------------
template <int K>
__device__ __forceinline__ void gemm128_pp(
    const u16* __restrict__ A0, const u16* __restrict__ B0,
    u16* lds, f32x4 (&acc)[4][4])
{
  const int tid = threadIdx.x;
  const int w = tid >> 6, l = tid & 63;
  const int wm = w >> 1, wn = w & 1;
  const int fr = l & 15;
  const int laneChunk = ((l >> 4) ^ ((fr >> 1) & 3)) << 3;
  const int laneA = (wm * 64 + fr) * 32 + laneChunk;
  const int laneB = (wn * 64 + fr) * 32 + laneChunk;
  u16* const ldsA = lds;                 // 3 slots x 8192 u16 (16 KB)
  u16* const ldsB = lds + 24576;         // 3 slots x 4096 u16 (8 KB)

  const int chunkS = ((tid & 3) ^ ((tid >> 3) & 3)) << 3;
  const int r0 = tid >> 2;               // 0..127
  const u16* const sA0 = A0 + (size_t)r0 * K + chunkS;
  const u16* const sA1 = A0 + (size_t)(r0 + 128) * K + chunkS;
  const u16* const sB0 = B0 + (size_t)r0 * K + chunkS;
  const int dOf = w * 512;

#define PSTAGE_A(j, slot) do {                                                 \
    u16* d_ = ldsA + (slot) * 8192 + dOf;                                      \
    GLL16(sA0 + (j) * 32, d_);                                                 \
    GLL16(sA1 + (j) * 32, d_ + 4096);                                          \
  } while (0)
#define PSTAGE_B(j, slot) do {                                                 \
    u16* d_ = ldsB + (slot) * 4096 + dOf;                                      \
    GLL16(sB0 + (j) * 32, d_);                                                 \
  } while (0)

  constexpr int NS = K / 32;
  bf16x8 aP[4], bP[4], aQ[4], bQ[4];     // statically-named ping-pong sets

  PSTAGE_B(0, 0); PSTAGE_A(0, 0);
  PSTAGE_B(1, 1); PSTAGE_A(1, 1);
  PSTAGE_B(2, 2); PSTAGE_A(2, 2);
  asm volatile("s_waitcnt vmcnt(6)\n\ts_barrier" ::: "memory");
#pragma unroll
  for (int i = 0; i < 4; ++i) aP[i] = *(const bf16x8*)(ldsA + laneA + i * 512);
#pragma unroll
  for (int i = 0; i < 4; ++i) bP[i] = *(const bf16x8*)(ldsB + laneB + i * 512);

#define KITER(jj, CA, CB, NA, NB) do {                                         \
    const int js_ = ((jj) + 3 < NS) ? (jj) + 3 : NS - 1;                       \
    const int sS_ = (jj) % 3;                                                  \
    const int sR_ = ((jj) + 1) % 3;                                            \
    asm volatile("s_waitcnt vmcnt(3) lgkmcnt(0)\n\ts_barrier" ::: "memory");   \
    const u16* const Ab_ = ldsA + sR_ * 8192;                                  \
    const u16* const Bb_ = ldsB + sR_ * 4096;                                  \
    _Pragma("unroll")                                                          \
    for (int i = 0; i < 4; ++i) NB[i] = *(const bf16x8*)(Bb_ + laneB + i * 512); \
    _Pragma("unroll")                                                          \
    for (int i = 0; i < 4; ++i) NA[i] = *(const bf16x8*)(Ab_ + laneA + i * 512); \
    PSTAGE_B(js_, sS_);                                                        \
    __builtin_amdgcn_s_setprio(1);                                             \
    _Pragma("unroll")                                                          \
    for (int mi = 0; mi < 2; ++mi)                                             \
      _Pragma("unroll")                                                        \
      for (int nj = 0; nj < 4; ++nj)                                           \
        acc[mi][nj] = __builtin_amdgcn_mfma_f32_16x16x32_bf16(                 \
            CA[mi], CB[nj], acc[mi][nj], 0, 0, 0);                             \
    __builtin_amdgcn_s_setprio(0);                                             \
    PSTAGE_A(js_, sS_);                                                        \
    __builtin_amdgcn_s_setprio(1);                                             \
    _Pragma("unroll")                                                          \
    for (int mi = 2; mi < 4; ++mi)                                             \
      _Pragma("unroll")                                                        \
      for (int nj = 0; nj < 4; ++nj)                                           \
        acc[mi][nj] = __builtin_amdgcn_mfma_f32_16x16x32_bf16(                 \
            CA[mi], CB[nj], acc[mi][nj], 0, 0, 0);                             \
    __builtin_amdgcn_s_setprio(0);                                             \
  } while (0)

  for (int j = 0; j < NS; j += 2) {      // NS even; static reg names
    KITER(j, aP, bP, aQ, bQ);
    KITER(j + 1, aQ, bQ, aP, bP);
  }
#undef KITER
#undef PSTAGE_A
#undef PSTAGE_B
}

// ---------------------------------------------------------------------------
// 256x256 ping-pong mainloop (scores) - R13, proven.
// ---------------------------------------------------------------------------
template <int K>
__device__ __forceinline__ void gemm8p_256sq_pp(
    const u16* __restrict__ A0, const u16* __restrict__ B0,
    u16* lds, f32x4 (&acc)[8][4])
{
  const int tid = threadIdx.x;
  const int w = tid >> 6, l = tid & 63;
  const int wm = w >> 2, wn = w & 3;
  const int fr = l & 15;
  const int laneChunk = ((l >> 4) ^ ((fr >> 1) & 3)) << 3;
  const int laneA = (wm * 128 + fr) * 32 + laneChunk;
  const int laneB = (wn * 64 + fr) * 32 + laneChunk;
  u16* const ldsA = lds;                 // 3 slots x 8192 u16 (16 KB)
  u16* const ldsB = lds + 24576;         // 3 slots x 8192 u16 (16 KB)

  const int chunkS = ((tid & 3) ^ ((tid >> 3) & 3)) << 3;
  const int r0 = tid >> 2;               // 0..127
  const u16* const sA0 = A0 + (size_t)r0 * K + chunkS;
  const u16* const sA1 = A0 + (size_t)(r0 + 128) * K + chunkS;
  const u16* const sB0 = B0 + (size_t)r0 * K + chunkS;
  const u16* const sB1 = B0 + (size_t)(r0 + 128) * K + chunkS;
  const int dOf = w * 512;

#define SSTAGE_A(j, slot) do {                                                 \
    u16* d_ = ldsA + (slot) * 8192 + dOf;                                      \
    GLL16(sA0 + (j) * 32, d_);                                                 \
    GLL16(sA1 + (j) * 32, d_ + 4096);                                          \
  } while (0)
#define SSTAGE_B(j, slot) do {                                                 \
    u16* d_ = ldsB + (slot) * 8192 + dOf;                                      \
    GLL16(sB0 + (j) * 32, d_);                                                 \
    GLL16(sB1 + (j) * 32, d_ + 4096);                                          \
  } while (0)

  constexpr int NS = K / 32;
  bf16x8 bP[4], aP0[4], aP1[4], bQ[4], aQ0[4], aQ1[4];

  SSTAGE_B(0, 0); SSTAGE_A(0, 0);
  SSTAGE_B(1, 1); SSTAGE_A(1, 1);
  SSTAGE_B(2, 2); SSTAGE_A(2, 2);
  asm volatile("s_waitcnt vmcnt(8)\n\ts_barrier" ::: "memory");
#pragma unroll
  for (int i = 0; i < 4; ++i) bP[i]  = *(const bf16x8*)(ldsB + laneB + i * 512);
#pragma unroll
  for (int i = 0; i < 4; ++i) aP0[i] = *(const bf16x8*)(ldsA + laneA + i * 512);
#pragma unroll
  for (int i = 0; i < 4; ++i) aP1[i] = *(const bf16x8*)(ldsA + laneA + (4 + i) * 512);

#define SITER(jj, CB, CA0, CA1, NB, NA0, NA1) do {                             \
    const int js_ = ((jj) + 3 < NS) ? (jj) + 3 : NS - 1;                       \
    const int sS_ = (jj) % 3;                                                  \
    const int sR_ = ((jj) + 1) % 3;                                            \
    asm volatile("s_waitcnt vmcnt(4) lgkmcnt(0)\n\ts_barrier" ::: "memory");   \
    const u16* const Ab_ = ldsA + sR_ * 8192;                                  \
    const u16* const Bb_ = ldsB + sR_ * 8192;                                  \
    _Pragma("unroll")                                                          \
    for (int i = 0; i < 4; ++i) NB[i]  = *(const bf16x8*)(Bb_ + laneB + i * 512); \
    _Pragma("unroll")                                                          \
    for (int i = 0; i < 4; ++i) NA0[i] = *(const bf16x8*)(Ab_ + laneA + i * 512); \
    SSTAGE_A(js_, sS_);                                                        \
    __builtin_amdgcn_s_setprio(1);                                             \
    _Pragma("unroll")                                                          \
    for (int mi = 0; mi < 4; ++mi)                                             \
      _Pragma("unroll")                                                        \
      for (int nj = 0; nj < 4; ++nj)                                           \
        acc[mi][nj] = __builtin_amdgcn_mfma_f32_16x16x32_bf16(                 \
            CA0[mi], CB[nj], acc[mi][nj], 0, 0, 0);                            \
    __builtin_amdgcn_s_setprio(0);                                             \
    _Pragma("unroll")                                                          \
    for (int i = 0; i < 4; ++i) NA1[i] = *(const bf16x8*)(Ab_ + laneA + (4 + i) * 512); \
    SSTAGE_B(js_, sS_);                                                        \
    __builtin_amdgcn_s_setprio(1);                                             \
    _Pragma("unroll")                                                          \
    for (int mi = 0; mi < 4; ++mi)                                             \
      _Pragma("unroll")                                                        \
      for (int nj = 0; nj < 4; ++nj)                                           \
        acc[4 + mi][nj] = __builtin_amdgcn_mfma_f32_16x16x32_bf16(             \
            CA1[mi], CB[nj], acc[4 + mi][nj], 0, 0, 0);                        \
    __builtin_amdgcn_s_setprio(0);                                             \
  } while (0)

  for (int j = 0; j < NS; j += 2) {
    SITER(j, bP, aP0, aP1, bQ, aQ0, aQ1);
    SITER(j + 1, bQ, aQ0, aQ1, bP, aP0, aP1);
  }
#undef SITER
#undef SSTAGE_A
#undef SSTAGE_B
}

// ---------------------------------------------------------------------------
// Kernels
// ---------------------------------------------------------------------------

__global__ void convert_x_kernel(const float* __restrict__ x, u16* __restrict__ xb) {
  int i = blockIdx.x * 256 + threadIdx.x;       // 2,097,152 threads * 4 floats
  float4 f = ((const float4*)x)[i];
  u16x4 o = { f2bf(f.x), f2bf(f.y), f2bf(f.z), f2bf(f.w) };
  ((u16x4*)xb)[i] = o;
}

// W[m][d][e] f32 -> Wt[m][e][d] bf16 (LDS-tiled transpose)
__global__ void convw_kernel(const float* __restrict__ W, u16* __restrict__ wT) {
  __shared__ float tile[32][33];
  const int mtx = blockIdx.z;
  const int e0 = blockIdx.x * 32, d0 = blockIdx.y * 32;
  const int tx = threadIdx.x, ty = threadIdx.y;
  const float* Wm = W + (size_t)mtx * 262144;
#pragma unroll
  for (int i = 0; i < 32; i += 8)
    tile[ty + i][tx] = Wm[(size_t)(d0 + ty + i) * 512 + e0 + tx];
  __syncthreads();
  u16* T = wT + (size_t)mtx * 262144;
#pragma unroll
  for (int i = 0; i < 32; i += 8)
    T[(size_t)(e0 + ty + i) * 512 + d0 + tx] = f2bf(tile[tx][ty + i]);
}

// QKV: xb[16384,512] . wT[1536,512]^T via 256x128 tiles (single frag set).
// Swizzle: xcd = id&7 owns batch xcd's m-rows: x 2MB + wT 1.5MB L2-resident.
__global__ __launch_bounds__(512, 4) void gemm_qkv128_kernel(
    const u16* __restrict__ xb, const u16* __restrict__ wT,
    u16* __restrict__ qb, u16* __restrict__ kb, u16* __restrict__ vt)
{
  __shared__ __align__(16) u16 lds[36864];   // 72 KB
  const int id = blockIdx.x;                 // 768 blocks
  const int xcd = id & 7, t = id >> 3;       // t: 0..95
  const int n0 = (t % 12) * 128;
  const int m0 = (xcd * 8 + t / 12) * 256;
  f32x4 acc[4][4] = {};
  gemm8p_256x128<512, false>(xb + (size_t)m0 * 512, wT + (size_t)n0 * 512, lds, acc, nullptr);

  const int tid = threadIdx.x, w = tid >> 6, l = tid & 63;
  const int wm = w >> 1, wn = w & 1;
  const int which = n0 >> 9;                 // 0=q 1=k 2=v
  const int eb = (n0 & 511) + wn * 64 + (l & 15);
  const int rb = m0 + wm * 64 + (l >> 4) * 4;
  if (which < 2) {
    u16* dst = which ? kb : qb;
#pragma unroll
    for (int mi = 0; mi < 4; ++mi)
#pragma unroll
      for (int nj = 0; nj < 4; ++nj) {
        const int row = rb + mi * 16;
        const int col = eb + nj * 16;
#pragma unroll
        for (int r = 0; r < 4; ++r)
          dst[(size_t)(row + r) * 512 + col] = f2bf(acc[mi][nj][r]);
      }
  } else {
#pragma unroll
    for (int mi = 0; mi < 4; ++mi)
#pragma unroll
      for (int nj = 0; nj < 4; ++nj) {
        const int s = rb + mi * 16;            // global row (b*2048+s)
        const int b = s >> 11, sl = s & 2047;
        const int e = eb + nj * 16;
        u16x4 pk;
#pragma unroll
        for (int r = 0; r < 4; ++r) pk[r] = f2bf(acc[mi][nj][r]);
        *(u16x4*)(vt + (size_t)b * 1048576 + (size_t)e * 2048 + sl) = pk;
      }
  }
}

// P[z] = exp(Q[z].K[z]^T * 0.125) -> bf16 (unnormalized; pv divides by
// rowsum). 256x256 ping-pong tiles; 512 blocks = 2 rounds; z = id&7.
__global__ __launch_bounds__(512, 2) void gemm_scores256_kernel(
    const u16* __restrict__ qb, const u16* __restrict__ kb, u16* __restrict__ attn)
{
  __shared__ __align__(16) u16 lds[49152];   // 96 KB
  const int id = blockIdx.x;                 // 512 blocks
  const int z = id & 7, t = id >> 3;         // t: 0..63
  const int n0 = (t & 7) * 256;
  const int m0 = (t >> 3) * 256;
  f32x4 acc[8][4] = {};
  gemm8p_256sq_pp<512>(qb + (size_t)z * 1048576 + (size_t)m0 * 512,
                       kb + (size_t)z * 1048576 + (size_t)n0 * 512, lds, acc);

  const int tid = threadIdx.x, w = tid >> 6, l = tid & 63;
  const int wm = w >> 2, wn = w & 3;
  u16* C = attn + (size_t)z * 4194304;
  const int rb = m0 + wm * 128 + (l >> 4) * 4;
  const int cb = n0 + wn * 64 + (l & 15);
#pragma unroll
  for (int mi = 0; mi < 8; ++mi)
#pragma unroll
    for (int nj = 0; nj < 4; ++nj) {
      const int row = rb + mi * 16;
      const int col = cb + nj * 16;
#pragma unroll
      for (int r = 0; r < 4; ++r)
        C[(size_t)(row + r) * 2048 + col] = f2bf(__expf(acc[mi][nj][r] * 0.125f));
    }
}

// rowsum[gr] = sum of attn row gr (16384 rows x 2048 bf16). Pure BW: 67MB,
// L3-hot after scores. 4096 blocks x 4 waves, 1 wave per row, 16B/lane x 4.
__global__ __launch_bounds__(256) void rowsum_kernel(
    const u16* __restrict__ attn, float* __restrict__ rsum)
{
  const int row = blockIdx.x * 4 + (threadIdx.x >> 6);
  const int l = threadIdx.x & 63;
  const u16* p = attn + (size_t)row * 2048;
  float s = 0.f;
#pragma unroll
  for (int c = 0; c < 4; ++c) {
    uint4 u = *(const uint4*)(p + (c * 64 + l) * 8);
    const u16* us = (const u16*)&u;
#pragma unroll
    for (int i = 0; i < 8; ++i) s += bf2f(us[i]);
  }
  for (int off = 32; off >= 1; off >>= 1) s += __shfl_xor(s, off);
  if (l == 0) rsum[row] = s;
}

// out[z] = (P[z].V[z]) / rowsum (FAST): ping-pong mainloop at bounds(512,2)
// (grid 256 = 1 blk/CU regardless; 256-VGPR budget fits acc + 2 frag sets).
// Normalization read from rsum in the epilogue - zero in-loop VALU.
__global__ __launch_bounds__(512, 2) void gemm_pv_pp_kernel(
    const u16* __restrict__ attn, const u16* __restrict__ vt,
    const float* __restrict__ rsum, float* __restrict__ out)
{
  __shared__ __align__(16) u16 lds[36864];   // 72 KB
  const int id = blockIdx.x;                 // 256 blocks
  const int z = id & 7;                      // id%8 = XCD (T1): one z per XCD
  const int j = id >> 3;                     // 0..31
  const int n0 = (j & 3) * 128;              // 4 n-tiles
  const int m0 = (j >> 2) * 256;             // 8 m-tiles
  f32x4 acc[4][4] = {};
  gemm128_pp<2048>(attn + (size_t)z * 4194304 + (size_t)m0 * 2048,
                   vt + (size_t)z * 1048576 + (size_t)n0 * 2048, lds, acc);

  const int tid = threadIdx.x, w = tid >> 6, l = tid & 63;
  const int wm = w >> 1, wn = w & 1;
  const int rb = m0 + wm * 64 + (l >> 4) * 4;
  const int cb = n0 + wn * 64 + (l & 15);
  float* C = out + (size_t)z * 1048576;
  const float* rz = rsum + (size_t)z * 2048;
#pragma unroll
  for (int mi = 0; mi < 4; ++mi)
#pragma unroll
    for (int r = 0; r < 4; ++r) {
      const float inv = 1.f / rz[rb + mi * 16 + r];
      const int row = rb + mi * 16 + r;
#pragma unroll
      for (int nj = 0; nj < 4; ++nj)
        C[(size_t)row * 512 + cb + nj * 16] = acc[mi][nj][r] * inv;
    }
}

// Fallback pv (ws lacks rsum tail): single-set loop + in-loop rowsum (R13).
__global__ __launch_bounds__(512, 4) void gemm_pv_fb_kernel(
    const u16* __restrict__ attn, const u16* __restrict__ vt,
    float* __restrict__ out)
{
  __shared__ __align__(16) u16 lds[36864];   // 72 KB
  __shared__ float rowsumLDS[256];
  const int id = blockIdx.x;                 // 256 blocks
  const int z = id & 7;
  const int j = id >> 3;
  const int n0 = (j & 3) * 128;
  const int m0 = (j >> 2) * 256;
  f32x4 acc[4][4] = {};
  float rs[4] = {0.f, 0.f, 0.f, 0.f};
  gemm8p_256x128<2048, true>(attn + (size_t)z * 4194304 + (size_t)m0 * 2048,
                             vt + (size_t)z * 1048576 + (size_t)n0 * 2048, lds, acc, rs);

  const int tid = threadIdx.x, w = tid >> 6, l = tid & 63;
  const int wm = w >> 1, wn = w & 1;
  __syncthreads();
#pragma unroll
  for (int mi = 0; mi < 4; ++mi) {
    rs[mi] += __shfl_xor(rs[mi], 16);
    rs[mi] += __shfl_xor(rs[mi], 32);
  }
  if ((l >> 4) == 0) {
#pragma unroll
    for (int mi = 0; mi < 4; ++mi)
      rowsumLDS[wm * 64 + mi * 16 + l] = rs[mi];
  }
  __syncthreads();

  float* C = out + (size_t)z * 1048576;
  const int rb = m0 + wm * 64 + (l >> 4) * 4;
  const int cb = n0 + wn * 64 + (l & 15);
#pragma unroll
  for (int mi = 0; mi < 4; ++mi)
#pragma unroll
    for (int r = 0; r < 4; ++r) {
      const float inv = 1.f / rowsumLDS[wm * 64 + mi * 16 + (l >> 4) * 4 + r];
      const int row = rb + mi * 16 + r;
#pragma unroll
      for (int nj = 0; nj < 4; ++nj)
        C[(size_t)row * 512 + cb + nj * 16] = acc[mi][nj][r] * inv;
    }
}

// ---------------------------------------------------------------------------
extern "C" void kernel_launch(void* const* d_in, const int* in_sizes, int n_in,
                              void* d_out, int out_size, void* d_ws, size_t ws_size,
                              hipStream_t stream) {
  const float* x = (const float*)d_in[0];   // [8,2048,512]
  const float* W = (const float*)d_in[1];   // [3,512,512]
  float* out = (float*)d_out;               // [8,2048,512]

  if (ws_size < 117440512) return;          // 112 MiB minimum
  u16* wsu  = (u16*)d_ws;
  u16* qb   = wsu;
  u16* kb   = qb + 8388608;
  u16* vt   = kb + 8388608;
  u16* attn = vt + 8388608;
  u16* xb   = attn;                         // alias: dead before scores written
  u16* wT   = attn + 8388608;               // alias: dead before scores written

  const bool fast = ws_size >= 117440512 + 65536;   // rsum[8][2048] f32 tail
  float* rsum = fast ? (float*)(wsu + 58720256) : nullptr;

  convert_x_kernel<<<8192, 256, 0, stream>>>(x, xb);
  convw_kernel<<<dim3(16, 16, 3), dim3(32, 8), 0, stream>>>(W, wT);
  gemm_qkv128_kernel<<<768, 512, 0, stream>>>(xb, wT, qb, kb, vt);
  gemm_scores256_kernel<<<512, 512, 0, stream>>>(qb, kb, attn);
  if (fast) {
    rowsum_kernel<<<4096, 256, 0, stream>>>(attn, rsum);
    gemm_pv_pp_kernel<<<256, 512, 0, stream>>>(attn, vt, rsum, out);
  } else {
    gemm_pv_fb_kernel<<<256, 512, 0, stream>>>(attn, vt, out);
  }
}

// Round 17
// 126.014 us; speedup vs baseline: 2.1670x; 1.0724x over previous
//
#include <hip/hip_runtime.h>

// SelfAttention: x[8,2048,512] f32, W[3,512,512] f32 -> out[8,2048,512] f32
// scale = 1/sqrt(64) = 0.125
//
// R17: R13 base (best measured, 132us) + pv rowsum moved to the MATRIX pipe:
// acc5[mi] = mfma(a[mi], ones, acc5[mi]) per slab (+4 MFMA/slab, absorbed -
// pv is latency-bound at MfmaUtil 26%) replaces the in-loop VALU rsum
// (32 add + 32 cvt per thread/slab = VALUBusy 35%, ~13.5us). MFMA C-layout
// puts rowsum for row (l>>4)*4+r in acc5[mi][r] on the exact lane that
// normalizes that row -> no shfl/LDS exchange. bounds(512,2): VGPR ~137
// fits 256-budget; pv grid 256 = 1 blk/CU regardless (R16 confirmed).

typedef unsigned short u16;
typedef unsigned int u32;

using bf16x8 = __attribute__((ext_vector_type(8))) short;   // 8 bf16 (4 VGPRs)
using f32x4  = __attribute__((ext_vector_type(4))) float;
using u16x4  = __attribute__((ext_vector_type(4))) u16;

__device__ __forceinline__ u16 f2bf(float f) {
  u32 u = __float_as_uint(f);
  u32 r = (u + 0x7FFFu + ((u >> 16) & 1u)) >> 16;   // RNE
  return (u16)r;
}
__device__ __forceinline__ float bf2f(u16 h) {
  return __uint_as_float(((u32)h) << 16);
}

#define GLL16(src, dst)                                                        \
  __builtin_amdgcn_global_load_lds(                                            \
      (const __attribute__((address_space(1))) void*)(src),                    \
      (__attribute__((address_space(3))) void*)(dst), 16, 0, 0)

// ---------------------------------------------------------------------------
// 256x128 single-frag-set mainloop (R10, proven): 8 waves 4Mx2N, acc[4][4],
// 3-slot BK=32, gate vmcnt(3)+barrier, one barrier per slab.
// ROWSUM_MFMA: also accumulate acc5[mi] += A x ones (rowsum in matrix pipe).
// ---------------------------------------------------------------------------
template <int K, bool ROWSUM_MFMA>
__device__ __forceinline__ void gemm8p_256x128(
    const u16* __restrict__ A0, const u16* __restrict__ B0,
    u16* lds, f32x4 (&acc)[4][4], f32x4* acc5)
{
  const int tid = threadIdx.x;
  const int w = tid >> 6, l = tid & 63;
  const int wm = w >> 1, wn = w & 1;
  const int fr = l & 15;
  const int laneChunk = ((l >> 4) ^ ((fr >> 1) & 3)) << 3;
  const int laneA = (wm * 64 + fr) * 32 + laneChunk;
  const int laneB = (wn * 64 + fr) * 32 + laneChunk;
  u16* const ldsA = lds;                 // 3 slots x 8192 u16 (16 KB)
  u16* const ldsB = lds + 24576;         // 3 slots x 4096 u16 (8 KB)

  const int chunkS = ((tid & 3) ^ ((tid >> 3) & 3)) << 3;
  const int r0 = tid >> 2;               // 0..127
  const u16* const sA0 = A0 + (size_t)r0 * K + chunkS;
  const u16* const sA1 = A0 + (size_t)(r0 + 128) * K + chunkS;
  const u16* const sB0 = B0 + (size_t)r0 * K + chunkS;
  const int dOf = w * 512;

  bf16x8 bOnes;
#pragma unroll
  for (int i = 0; i < 8; ++i) bOnes[i] = (short)0x3F80;   // bf16 1.0

#define PSTAGE_A(j, slot) do {                                                 \
    u16* d_ = ldsA + (slot) * 8192 + dOf;                                      \
    GLL16(sA0 + (j) * 32, d_);                                                 \
    GLL16(sA1 + (j) * 32, d_ + 4096);                                          \
  } while (0)
#define PSTAGE_B(j, slot) do {                                                 \
    u16* d_ = ldsB + (slot) * 4096 + dOf;                                      \
    GLL16(sB0 + (j) * 32, d_);                                                 \
  } while (0)

  PSTAGE_B(0, 0); PSTAGE_A(0, 0);
  PSTAGE_B(1, 1); PSTAGE_A(1, 1);

  constexpr int NS = K / 32;
  int slot = 0;
  for (int j = 0; j < NS; ++j) {
    const int jn = (j + 2 < NS) ? (j + 2) : (NS - 1);
    int slotn = slot + 2; if (slotn >= 3) slotn -= 3;

    asm volatile("s_waitcnt vmcnt(3)\n\ts_barrier" ::: "memory");

    const u16* const Ab = ldsA + slot * 8192;
    const u16* const Bb = ldsB + slot * 4096;
    bf16x8 a[4], b[4];
#pragma unroll
    for (int i = 0; i < 4; ++i) a[i] = *(const bf16x8*)(Ab + laneA + i * 512);
#pragma unroll
    for (int i = 0; i < 4; ++i) b[i] = *(const bf16x8*)(Bb + laneB + i * 512);
    PSTAGE_B(jn, slotn);
    __builtin_amdgcn_s_setprio(1);
#pragma unroll
    for (int mi = 0; mi < 2; ++mi)
#pragma unroll
      for (int nj = 0; nj < 4; ++nj)
        acc[mi][nj] = __builtin_amdgcn_mfma_f32_16x16x32_bf16(a[mi], b[nj], acc[mi][nj], 0, 0, 0);
    __builtin_amdgcn_s_setprio(0);
    PSTAGE_A(jn, slotn);
    __builtin_amdgcn_s_setprio(1);
#pragma unroll
    for (int mi = 2; mi < 4; ++mi)
#pragma unroll
      for (int nj = 0; nj < 4; ++nj)
        acc[mi][nj] = __builtin_amdgcn_mfma_f32_16x16x32_bf16(a[mi], b[nj], acc[mi][nj], 0, 0, 0);
    if (ROWSUM_MFMA) {
#pragma unroll
      for (int mi = 0; mi < 4; ++mi)
        acc5[mi] = __builtin_amdgcn_mfma_f32_16x16x32_bf16(a[mi], bOnes, acc5[mi], 0, 0, 0);
    }
    __builtin_amdgcn_s_setprio(0);

    slot = (slot == 2) ? 0 : slot + 1;
  }
#undef PSTAGE_A
#undef PSTAGE_B
}

// ---------------------------------------------------------------------------
// 256x256 ping-pong mainloop (scores) - R13, proven.
// ---------------------------------------------------------------------------
template <int K>
__device__ __forceinline__ void gemm8p_256sq_pp(
    const u16* __restrict__ A0, const u16* __restrict__ B0,
    u16* lds, f32x4 (&acc)[8][4])
{
  const int tid = threadIdx.x;
  const int w = tid >> 6, l = tid & 63;
  const int wm = w >> 2, wn = w & 3;
  const int fr = l & 15;
  const int laneChunk = ((l >> 4) ^ ((fr >> 1) & 3)) << 3;
  const int laneA = (wm * 128 + fr) * 32 + laneChunk;
  const int laneB = (wn * 64 + fr) * 32 + laneChunk;
  u16* const ldsA = lds;                 // 3 slots x 8192 u16 (16 KB)
  u16* const ldsB = lds + 24576;         // 3 slots x 8192 u16 (16 KB)

  const int chunkS = ((tid & 3) ^ ((tid >> 3) & 3)) << 3;
  const int r0 = tid >> 2;               // 0..127
  const u16* const sA0 = A0 + (size_t)r0 * K + chunkS;
  const u16* const sA1 = A0 + (size_t)(r0 + 128) * K + chunkS;
  const u16* const sB0 = B0 + (size_t)r0 * K + chunkS;
  const u16* const sB1 = B0 + (size_t)(r0 + 128) * K + chunkS;
  const int dOf = w * 512;

#define SSTAGE_A(j, slot) do {                                                 \
    u16* d_ = ldsA + (slot) * 8192 + dOf;                                      \
    GLL16(sA0 + (j) * 32, d_);                                                 \
    GLL16(sA1 + (j) * 32, d_ + 4096);                                          \
  } while (0)
#define SSTAGE_B(j, slot) do {                                                 \
    u16* d_ = ldsB + (slot) * 8192 + dOf;                                      \
    GLL16(sB0 + (j) * 32, d_);                                                 \
    GLL16(sB1 + (j) * 32, d_ + 4096);                                          \
  } while (0)

  constexpr int NS = K / 32;
  bf16x8 bP[4], aP0[4], aP1[4], bQ[4], aQ0[4], aQ1[4];

  SSTAGE_B(0, 0); SSTAGE_A(0, 0);
  SSTAGE_B(1, 1); SSTAGE_A(1, 1);
  SSTAGE_B(2, 2); SSTAGE_A(2, 2);
  asm volatile("s_waitcnt vmcnt(8)\n\ts_barrier" ::: "memory");
#pragma unroll
  for (int i = 0; i < 4; ++i) bP[i]  = *(const bf16x8*)(ldsB + laneB + i * 512);
#pragma unroll
  for (int i = 0; i < 4; ++i) aP0[i] = *(const bf16x8*)(ldsA + laneA + i * 512);
#pragma unroll
  for (int i = 0; i < 4; ++i) aP1[i] = *(const bf16x8*)(ldsA + laneA + (4 + i) * 512);

#define SITER(jj, CB, CA0, CA1, NB, NA0, NA1) do {                             \
    const int js_ = ((jj) + 3 < NS) ? (jj) + 3 : NS - 1;                       \
    const int sS_ = (jj) % 3;                                                  \
    const int sR_ = ((jj) + 1) % 3;                                            \
    asm volatile("s_waitcnt vmcnt(4) lgkmcnt(0)\n\ts_barrier" ::: "memory");   \
    const u16* const Ab_ = ldsA + sR_ * 8192;                                  \
    const u16* const Bb_ = ldsB + sR_ * 8192;                                  \
    _Pragma("unroll")                                                          \
    for (int i = 0; i < 4; ++i) NB[i]  = *(const bf16x8*)(Bb_ + laneB + i * 512); \
    _Pragma("unroll")                                                          \
    for (int i = 0; i < 4; ++i) NA0[i] = *(const bf16x8*)(Ab_ + laneA + i * 512); \
    SSTAGE_A(js_, sS_);                                                        \
    __builtin_amdgcn_s_setprio(1);                                             \
    _Pragma("unroll")                                                          \
    for (int mi = 0; mi < 4; ++mi)                                             \
      _Pragma("unroll")                                                        \
      for (int nj = 0; nj < 4; ++nj)                                           \
        acc[mi][nj] = __builtin_amdgcn_mfma_f32_16x16x32_bf16(                 \
            CA0[mi], CB[nj], acc[mi][nj], 0, 0, 0);                            \
    __builtin_amdgcn_s_setprio(0);                                             \
    _Pragma("unroll")                                                          \
    for (int i = 0; i < 4; ++i) NA1[i] = *(const bf16x8*)(Ab_ + laneA + (4 + i) * 512); \
    SSTAGE_B(js_, sS_);                                                        \
    __builtin_amdgcn_s_setprio(1);                                             \
    _Pragma("unroll")                                                          \
    for (int mi = 0; mi < 4; ++mi)                                             \
      _Pragma("unroll")                                                        \
      for (int nj = 0; nj < 4; ++nj)                                           \
        acc[4 + mi][nj] = __builtin_amdgcn_mfma_f32_16x16x32_bf16(             \
            CA1[mi], CB[nj], acc[4 + mi][nj], 0, 0, 0);                        \
    __builtin_amdgcn_s_setprio(0);                                             \
  } while (0)

  for (int j = 0; j < NS; j += 2) {
    SITER(j, bP, aP0, aP1, bQ, aQ0, aQ1);
    SITER(j + 1, bQ, aQ0, aQ1, bP, aP0, aP1);
  }
#undef SITER
#undef SSTAGE_A
#undef SSTAGE_B
}

// ---------------------------------------------------------------------------
// Kernels
// ---------------------------------------------------------------------------

__global__ void convert_x_kernel(const float* __restrict__ x, u16* __restrict__ xb) {
  int i = blockIdx.x * 256 + threadIdx.x;       // 2,097,152 threads * 4 floats
  float4 f = ((const float4*)x)[i];
  u16x4 o = { f2bf(f.x), f2bf(f.y), f2bf(f.z), f2bf(f.w) };
  ((u16x4*)xb)[i] = o;
}

// W[m][d][e] f32 -> Wt[m][e][d] bf16 (LDS-tiled transpose)
__global__ void convw_kernel(const float* __restrict__ W, u16* __restrict__ wT) {
  __shared__ float tile[32][33];
  const int mtx = blockIdx.z;
  const int e0 = blockIdx.x * 32, d0 = blockIdx.y * 32;
  const int tx = threadIdx.x, ty = threadIdx.y;
  const float* Wm = W + (size_t)mtx * 262144;
#pragma unroll
  for (int i = 0; i < 32; i += 8)
    tile[ty + i][tx] = Wm[(size_t)(d0 + ty + i) * 512 + e0 + tx];
  __syncthreads();
  u16* T = wT + (size_t)mtx * 262144;
#pragma unroll
  for (int i = 0; i < 32; i += 8)
    T[(size_t)(e0 + ty + i) * 512 + d0 + tx] = f2bf(tile[tx][ty + i]);
}

// QKV: xb[16384,512] . wT[1536,512]^T via 256x128 tiles (single frag set).
// Swizzle: xcd = id&7 owns batch xcd's m-rows: x 2MB + wT 1.5MB L2-resident.
__global__ __launch_bounds__(512, 4) void gemm_qkv128_kernel(
    const u16* __restrict__ xb, const u16* __restrict__ wT,
    u16* __restrict__ qb, u16* __restrict__ kb, u16* __restrict__ vt)
{
  __shared__ __align__(16) u16 lds[36864];   // 72 KB
  const int id = blockIdx.x;                 // 768 blocks
  const int xcd = id & 7, t = id >> 3;       // t: 0..95
  const int n0 = (t % 12) * 128;
  const int m0 = (xcd * 8 + t / 12) * 256;
  f32x4 acc[4][4] = {};
  gemm8p_256x128<512, false>(xb + (size_t)m0 * 512, wT + (size_t)n0 * 512, lds, acc, nullptr);

  const int tid = threadIdx.x, w = tid >> 6, l = tid & 63;
  const int wm = w >> 1, wn = w & 1;
  const int which = n0 >> 9;                 // 0=q 1=k 2=v
  const int eb = (n0 & 511) + wn * 64 + (l & 15);
  const int rb = m0 + wm * 64 + (l >> 4) * 4;
  if (which < 2) {
    u16* dst = which ? kb : qb;
#pragma unroll
    for (int mi = 0; mi < 4; ++mi)
#pragma unroll
      for (int nj = 0; nj < 4; ++nj) {
        const int row = rb + mi * 16;
        const int col = eb + nj * 16;
#pragma unroll
        for (int r = 0; r < 4; ++r)
          dst[(size_t)(row + r) * 512 + col] = f2bf(acc[mi][nj][r]);
      }
  } else {
#pragma unroll
    for (int mi = 0; mi < 4; ++mi)
#pragma unroll
      for (int nj = 0; nj < 4; ++nj) {
        const int s = rb + mi * 16;            // global row (b*2048+s)
        const int b = s >> 11, sl = s & 2047;
        const int e = eb + nj * 16;
        u16x4 pk;
#pragma unroll
        for (int r = 0; r < 4; ++r) pk[r] = f2bf(acc[mi][nj][r]);
        *(u16x4*)(vt + (size_t)b * 1048576 + (size_t)e * 2048 + sl) = pk;
      }
  }
}

// P[z] = exp(Q[z].K[z]^T * 0.125) -> bf16 (unnormalized; pv divides by
// rowsum). 256x256 ping-pong tiles; 512 blocks = 2 rounds; z = id&7.
__global__ __launch_bounds__(512, 2) void gemm_scores256_kernel(
    const u16* __restrict__ qb, const u16* __restrict__ kb, u16* __restrict__ attn)
{
  __shared__ __align__(16) u16 lds[49152];   // 96 KB
  const int id = blockIdx.x;                 // 512 blocks
  const int z = id & 7, t = id >> 3;         // t: 0..63
  const int n0 = (t & 7) * 256;
  const int m0 = (t >> 3) * 256;
  f32x4 acc[8][4] = {};
  gemm8p_256sq_pp<512>(qb + (size_t)z * 1048576 + (size_t)m0 * 512,
                       kb + (size_t)z * 1048576 + (size_t)n0 * 512, lds, acc);

  const int tid = threadIdx.x, w = tid >> 6, l = tid & 63;
  const int wm = w >> 2, wn = w & 3;
  u16* C = attn + (size_t)z * 4194304;
  const int rb = m0 + wm * 128 + (l >> 4) * 4;
  const int cb = n0 + wn * 64 + (l & 15);
#pragma unroll
  for (int mi = 0; mi < 8; ++mi)
#pragma unroll
    for (int nj = 0; nj < 4; ++nj) {
      const int row = rb + mi * 16;
      const int col = cb + nj * 16;
#pragma unroll
      for (int r = 0; r < 4; ++r)
        C[(size_t)(row + r) * 2048 + col] = f2bf(__expf(acc[mi][nj][r] * 0.125f));
    }
}

// out[z] = (P[z].V[z]) / rowsum. Rowsum computed IN the matrix pipe:
// acc5[mi] += A x ones per slab; C-layout puts the sum for row
// rb+mi*16+(l>>4)*4+r in acc5[mi][r] on the normalizing lane (no shfl).
__global__ __launch_bounds__(512, 2) void gemm_pv8p_kernel(
    const u16* __restrict__ attn, const u16* __restrict__ vt, float* __restrict__ out)
{
  __shared__ __align__(16) u16 lds[36864];   // 72 KB
  const int id = blockIdx.x;                 // 256 blocks
  const int z = id & 7;                      // id%8 = XCD (T1): one z per XCD
  const int j = id >> 3;                     // 0..31
  const int n0 = (j & 3) * 128;              // 4 n-tiles
  const int m0 = (j >> 2) * 256;             // 8 m-tiles
  f32x4 acc[4][4] = {};
  f32x4 acc5[4] = {};
  gemm8p_256x128<2048, true>(attn + (size_t)z * 4194304 + (size_t)m0 * 2048,
                             vt + (size_t)z * 1048576 + (size_t)n0 * 2048, lds, acc, acc5);

  const int tid = threadIdx.x, w = tid >> 6, l = tid & 63;
  const int wm = w >> 1, wn = w & 1;
  const int rb = m0 + wm * 64 + (l >> 4) * 4;
  const int cb = n0 + wn * 64 + (l & 15);
  float* C = out + (size_t)z * 1048576;
#pragma unroll
  for (int mi = 0; mi < 4; ++mi)
#pragma unroll
    for (int r = 0; r < 4; ++r) {
      const float inv = 1.f / acc5[mi][r];
      const int row = rb + mi * 16 + r;
#pragma unroll
      for (int nj = 0; nj < 4; ++nj)
        C[(size_t)row * 512 + cb + nj * 16] = acc[mi][nj][r] * inv;
    }
}

// ---------------------------------------------------------------------------
extern "C" void kernel_launch(void* const* d_in, const int* in_sizes, int n_in,
                              void* d_out, int out_size, void* d_ws, size_t ws_size,
                              hipStream_t stream) {
  const float* x = (const float*)d_in[0];   // [8,2048,512]
  const float* W = (const float*)d_in[1];   // [3,512,512]
  float* out = (float*)d_out;               // [8,2048,512]

  if (ws_size < 117440512) return;          // 112 MiB needed
  u16* wsu  = (u16*)d_ws;
  u16* qb   = wsu;
  u16* kb   = qb + 8388608;
  u16* vt   = kb + 8388608;
  u16* attn = vt + 8388608;
  u16* xb   = attn;                         // alias: dead before scores written
  u16* wT   = attn + 8388608;               // alias: dead before scores written

  convert_x_kernel<<<8192, 256, 0, stream>>>(x, xb);
  convw_kernel<<<dim3(16, 16, 3), dim3(32, 8), 0, stream>>>(W, wT);
  gemm_qkv128_kernel<<<768, 512, 0, stream>>>(xb, wT, qb, kb, vt);
  gemm_scores256_kernel<<<512, 512, 0, stream>>>(qb, kb, attn);
  gemm_pv8p_kernel<<<256, 512, 0, stream>>>(attn, vt, out);
}

// Round 18
// 123.967 us; speedup vs baseline: 2.2028x; 1.0165x over previous
//
#include <hip/hip_runtime.h>

// SelfAttention: x[8,2048,512] f32, W[3,512,512] f32 -> out[8,2048,512] f32
// scale = 1/sqrt(64) = 0.125
//
// R18: 4-slot ping-pong for scores AND pv - removes the per-slab
// lgkmcnt(0) full drain (only existed to close the 3-slot overwrite race;
// with 4 slots the read-slot is rewritten 4 slabs later and the compiler's
// fine-grained lgkm wait before next iter's MFMA orders everything).
// LDS 96->128KB (scores) / 72->96KB (pv): both 1 blk/CU already, free.
// pv also gains the pp frag pipeline (VGPR ~190 < 256 at bounds(512,2))
// and keeps the R17 MFMA-rowsum (acc5 += A x ones). qkv unchanged.

typedef unsigned short u16;
typedef unsigned int u32;

using bf16x8 = __attribute__((ext_vector_type(8))) short;   // 8 bf16 (4 VGPRs)
using f32x4  = __attribute__((ext_vector_type(4))) float;
using u16x4  = __attribute__((ext_vector_type(4))) u16;

__device__ __forceinline__ u16 f2bf(float f) {
  u32 u = __float_as_uint(f);
  u32 r = (u + 0x7FFFu + ((u >> 16) & 1u)) >> 16;   // RNE
  return (u16)r;
}
__device__ __forceinline__ float bf2f(u16 h) {
  return __uint_as_float(((u32)h) << 16);
}

#define GLL16(src, dst)                                                        \
  __builtin_amdgcn_global_load_lds(                                            \
      (const __attribute__((address_space(1))) void*)(src),                    \
      (__attribute__((address_space(3))) void*)(dst), 16, 0, 0)

// ---------------------------------------------------------------------------
// 256x128 single-frag-set mainloop (qkv): 8 waves 4Mx2N, acc[4][4], 3-slot
// BK=32, gate vmcnt(3)+barrier. bounds(512,4), 72KB -> 2 blk/CU.
// ---------------------------------------------------------------------------
template <int K>
__device__ __forceinline__ void gemm8p_256x128(
    const u16* __restrict__ A0, const u16* __restrict__ B0,
    u16* lds, f32x4 (&acc)[4][4])
{
  const int tid = threadIdx.x;
  const int w = tid >> 6, l = tid & 63;
  const int wm = w >> 1, wn = w & 1;
  const int fr = l & 15;
  const int laneChunk = ((l >> 4) ^ ((fr >> 1) & 3)) << 3;
  const int laneA = (wm * 64 + fr) * 32 + laneChunk;
  const int laneB = (wn * 64 + fr) * 32 + laneChunk;
  u16* const ldsA = lds;                 // 3 slots x 8192 u16 (16 KB)
  u16* const ldsB = lds + 24576;         // 3 slots x 4096 u16 (8 KB)

  const int chunkS = ((tid & 3) ^ ((tid >> 3) & 3)) << 3;
  const int r0 = tid >> 2;               // 0..127
  const u16* const sA0 = A0 + (size_t)r0 * K + chunkS;
  const u16* const sA1 = A0 + (size_t)(r0 + 128) * K + chunkS;
  const u16* const sB0 = B0 + (size_t)r0 * K + chunkS;
  const int dOf = w * 512;

#define PSTAGE_A(j, slot) do {                                                 \
    u16* d_ = ldsA + (slot) * 8192 + dOf;                                      \
    GLL16(sA0 + (j) * 32, d_);                                                 \
    GLL16(sA1 + (j) * 32, d_ + 4096);                                          \
  } while (0)
#define PSTAGE_B(j, slot) do {                                                 \
    u16* d_ = ldsB + (slot) * 4096 + dOf;                                      \
    GLL16(sB0 + (j) * 32, d_);                                                 \
  } while (0)

  PSTAGE_B(0, 0); PSTAGE_A(0, 0);
  PSTAGE_B(1, 1); PSTAGE_A(1, 1);

  constexpr int NS = K / 32;
  int slot = 0;
  for (int j = 0; j < NS; ++j) {
    const int jn = (j + 2 < NS) ? (j + 2) : (NS - 1);
    int slotn = slot + 2; if (slotn >= 3) slotn -= 3;

    asm volatile("s_waitcnt vmcnt(3)\n\ts_barrier" ::: "memory");

    const u16* const Ab = ldsA + slot * 8192;
    const u16* const Bb = ldsB + slot * 4096;
    bf16x8 a[4], b[4];
#pragma unroll
    for (int i = 0; i < 4; ++i) a[i] = *(const bf16x8*)(Ab + laneA + i * 512);
#pragma unroll
    for (int i = 0; i < 4; ++i) b[i] = *(const bf16x8*)(Bb + laneB + i * 512);
    PSTAGE_B(jn, slotn);
    __builtin_amdgcn_s_setprio(1);
#pragma unroll
    for (int mi = 0; mi < 2; ++mi)
#pragma unroll
      for (int nj = 0; nj < 4; ++nj)
        acc[mi][nj] = __builtin_amdgcn_mfma_f32_16x16x32_bf16(a[mi], b[nj], acc[mi][nj], 0, 0, 0);
    __builtin_amdgcn_s_setprio(0);
    PSTAGE_A(jn, slotn);
    __builtin_amdgcn_s_setprio(1);
#pragma unroll
    for (int mi = 2; mi < 4; ++mi)
#pragma unroll
      for (int nj = 0; nj < 4; ++nj)
        acc[mi][nj] = __builtin_amdgcn_mfma_f32_16x16x32_bf16(a[mi], b[nj], acc[mi][nj], 0, 0, 0);
    __builtin_amdgcn_s_setprio(0);

    slot = (slot == 2) ? 0 : slot + 1;
  }
#undef PSTAGE_A
#undef PSTAGE_B
}

// ---------------------------------------------------------------------------
// 256x128 4-slot ping-pong mainloop (pv): frags[j+1] read during MFMA[j];
// stage slab j+3 into slot (j+3)&3; gate vmcnt(3) ONLY (no lgkm drain -
// read slot rewritten 4 slabs later; compiler's lgkm wait before next
// iter's MFMA + the barrier order it). ROWSUM: acc5 += A x ones (R17).
// LDS 4 x 24KB = 96KB; bounds(512,2) (pv grid 256 = 1 blk/CU anyway).
// ---------------------------------------------------------------------------
template <int K>
__device__ __forceinline__ void gemm128_pp4(
    const u16* __restrict__ A0, const u16* __restrict__ B0,
    u16* lds, f32x4 (&acc)[4][4], f32x4 (&acc5)[4])
{
  const int tid = threadIdx.x;
  const int w = tid >> 6, l = tid & 63;
  const int wm = w >> 1, wn = w & 1;
  const int fr = l & 15;
  const int laneChunk = ((l >> 4) ^ ((fr >> 1) & 3)) << 3;
  const int laneA = (wm * 64 + fr) * 32 + laneChunk;
  const int laneB = (wn * 64 + fr) * 32 + laneChunk;
  u16* const ldsA = lds;                 // 4 slots x 8192 u16 (16 KB)
  u16* const ldsB = lds + 32768;         // 4 slots x 4096 u16 (8 KB)

  const int chunkS = ((tid & 3) ^ ((tid >> 3) & 3)) << 3;
  const int r0 = tid >> 2;               // 0..127
  const u16* const sA0 = A0 + (size_t)r0 * K + chunkS;
  const u16* const sA1 = A0 + (size_t)(r0 + 128) * K + chunkS;
  const u16* const sB0 = B0 + (size_t)r0 * K + chunkS;
  const int dOf = w * 512;

  bf16x8 bOnes;
#pragma unroll
  for (int i = 0; i < 8; ++i) bOnes[i] = (short)0x3F80;   // bf16 1.0

#define PSTAGE_A(j, slot) do {                                                 \
    u16* d_ = ldsA + (slot) * 8192 + dOf;                                      \
    GLL16(sA0 + (j) * 32, d_);                                                 \
    GLL16(sA1 + (j) * 32, d_ + 4096);                                          \
  } while (0)
#define PSTAGE_B(j, slot) do {                                                 \
    u16* d_ = ldsB + (slot) * 4096 + dOf;                                      \
    GLL16(sB0 + (j) * 32, d_);                                                 \
  } while (0)

  constexpr int NS = K / 32;
  bf16x8 aP[4], bP[4], aQ[4], bQ[4];     // statically-named ping-pong sets

  PSTAGE_B(0, 0); PSTAGE_A(0, 0);
  PSTAGE_B(1, 1); PSTAGE_A(1, 1);
  PSTAGE_B(2, 2); PSTAGE_A(2, 2);
  asm volatile("s_waitcnt vmcnt(6)\n\ts_barrier" ::: "memory");
#pragma unroll
  for (int i = 0; i < 4; ++i) aP[i] = *(const bf16x8*)(ldsA + laneA + i * 512);
#pragma unroll
  for (int i = 0; i < 4; ++i) bP[i] = *(const bf16x8*)(ldsB + laneB + i * 512);

#define KITER(jj, CA, CB, NA, NB) do {                                         \
    const int js_ = ((jj) + 3 < NS) ? (jj) + 3 : NS - 1;                       \
    const int sS_ = ((jj) + 3) & 3;                                            \
    const int sR_ = ((jj) + 1) & 3;                                            \
    asm volatile("s_waitcnt vmcnt(3)\n\ts_barrier" ::: "memory");              \
    const u16* const Ab_ = ldsA + sR_ * 8192;                                  \
    const u16* const Bb_ = ldsB + sR_ * 4096;                                  \
    _Pragma("unroll")                                                          \
    for (int i = 0; i < 4; ++i) NB[i] = *(const bf16x8*)(Bb_ + laneB + i * 512); \
    _Pragma("unroll")                                                          \
    for (int i = 0; i < 4; ++i) NA[i] = *(const bf16x8*)(Ab_ + laneA + i * 512); \
    PSTAGE_B(js_, sS_);                                                        \
    __builtin_amdgcn_s_setprio(1);                                             \
    _Pragma("unroll")                                                          \
    for (int mi = 0; mi < 2; ++mi)                                             \
      _Pragma("unroll")                                                        \
      for (int nj = 0; nj < 4; ++nj)                                           \
        acc[mi][nj] = __builtin_amdgcn_mfma_f32_16x16x32_bf16(                 \
            CA[mi], CB[nj], acc[mi][nj], 0, 0, 0);                             \
    __builtin_amdgcn_s_setprio(0);                                             \
    PSTAGE_A(js_, sS_);                                                        \
    __builtin_amdgcn_s_setprio(1);                                             \
    _Pragma("unroll")                                                          \
    for (int mi = 2; mi < 4; ++mi)                                             \
      _Pragma("unroll")                                                        \
      for (int nj = 0; nj < 4; ++nj)                                           \
        acc[mi][nj] = __builtin_amdgcn_mfma_f32_16x16x32_bf16(                 \
            CA[mi], CB[nj], acc[mi][nj], 0, 0, 0);                             \
    _Pragma("unroll")                                                          \
    for (int mi = 0; mi < 4; ++mi)                                             \
      acc5[mi] = __builtin_amdgcn_mfma_f32_16x16x32_bf16(                      \
          CA[mi], bOnes, acc5[mi], 0, 0, 0);                                   \
    __builtin_amdgcn_s_setprio(0);                                             \
  } while (0)

  for (int j = 0; j < NS; j += 2) {      // NS even; static reg names
    KITER(j, aP, bP, aQ, bQ);
    KITER(j + 1, aQ, bQ, aP, bP);
  }
#undef KITER
#undef PSTAGE_A
#undef PSTAGE_B
}

// ---------------------------------------------------------------------------
// 256x256 4-slot ping-pong mainloop (scores): as R13's pp but 4 slots,
// gate vmcnt(4) ONLY (no lgkm drain). LDS 4 x 32KB = 128KB, 1 blk/CU.
// ---------------------------------------------------------------------------
template <int K>
__device__ __forceinline__ void gemm8p_256sq_pp4(
    const u16* __restrict__ A0, const u16* __restrict__ B0,
    u16* lds, f32x4 (&acc)[8][4])
{
  const int tid = threadIdx.x;
  const int w = tid >> 6, l = tid & 63;
  const int wm = w >> 2, wn = w & 3;
  const int fr = l & 15;
  const int laneChunk = ((l >> 4) ^ ((fr >> 1) & 3)) << 3;
  const int laneA = (wm * 128 + fr) * 32 + laneChunk;
  const int laneB = (wn * 64 + fr) * 32 + laneChunk;
  u16* const ldsA = lds;                 // 4 slots x 8192 u16 (16 KB)
  u16* const ldsB = lds + 32768;         // 4 slots x 8192 u16 (16 KB)

  const int chunkS = ((tid & 3) ^ ((tid >> 3) & 3)) << 3;
  const int r0 = tid >> 2;               // 0..127
  const u16* const sA0 = A0 + (size_t)r0 * K + chunkS;
  const u16* const sA1 = A0 + (size_t)(r0 + 128) * K + chunkS;
  const u16* const sB0 = B0 + (size_t)r0 * K + chunkS;
  const u16* const sB1 = B0 + (size_t)(r0 + 128) * K + chunkS;
  const int dOf = w * 512;

#define SSTAGE_A(j, slot) do {                                                 \
    u16* d_ = ldsA + (slot) * 8192 + dOf;                                      \
    GLL16(sA0 + (j) * 32, d_);                                                 \
    GLL16(sA1 + (j) * 32, d_ + 4096);                                          \
  } while (0)
#define SSTAGE_B(j, slot) do {                                                 \
    u16* d_ = ldsB + (slot) * 8192 + dOf;                                      \
    GLL16(sB0 + (j) * 32, d_);                                                 \
    GLL16(sB1 + (j) * 32, d_ + 4096);                                          \
  } while (0)

  constexpr int NS = K / 32;
  bf16x8 bP[4], aP0[4], aP1[4], bQ[4], aQ0[4], aQ1[4];

  SSTAGE_B(0, 0); SSTAGE_A(0, 0);
  SSTAGE_B(1, 1); SSTAGE_A(1, 1);
  SSTAGE_B(2, 2); SSTAGE_A(2, 2);
  asm volatile("s_waitcnt vmcnt(8)\n\ts_barrier" ::: "memory");
#pragma unroll
  for (int i = 0; i < 4; ++i) bP[i]  = *(const bf16x8*)(ldsB + laneB + i * 512);
#pragma unroll
  for (int i = 0; i < 4; ++i) aP0[i] = *(const bf16x8*)(ldsA + laneA + i * 512);
#pragma unroll
  for (int i = 0; i < 4; ++i) aP1[i] = *(const bf16x8*)(ldsA + laneA + (4 + i) * 512);

#define SITER(jj, CB, CA0, CA1, NB, NA0, NA1) do {                             \
    const int js_ = ((jj) + 3 < NS) ? (jj) + 3 : NS - 1;                       \
    const int sS_ = ((jj) + 3) & 3;                                            \
    const int sR_ = ((jj) + 1) & 3;                                            \
    asm volatile("s_waitcnt vmcnt(4)\n\ts_barrier" ::: "memory");              \
    const u16* const Ab_ = ldsA + sR_ * 8192;                                  \
    const u16* const Bb_ = ldsB + sR_ * 8192;                                  \
    _Pragma("unroll")                                                          \
    for (int i = 0; i < 4; ++i) NB[i]  = *(const bf16x8*)(Bb_ + laneB + i * 512); \
    _Pragma("unroll")                                                          \
    for (int i = 0; i < 4; ++i) NA0[i] = *(const bf16x8*)(Ab_ + laneA + i * 512); \
    SSTAGE_A(js_, sS_);                                                        \
    __builtin_amdgcn_s_setprio(1);                                             \
    _Pragma("unroll")                                                          \
    for (int mi = 0; mi < 4; ++mi)                                             \
      _Pragma("unroll")                                                        \
      for (int nj = 0; nj < 4; ++nj)                                           \
        acc[mi][nj] = __builtin_amdgcn_mfma_f32_16x16x32_bf16(                 \
            CA0[mi], CB[nj], acc[mi][nj], 0, 0, 0);                            \
    __builtin_amdgcn_s_setprio(0);                                             \
    _Pragma("unroll")                                                          \
    for (int i = 0; i < 4; ++i) NA1[i] = *(const bf16x8*)(Ab_ + laneA + (4 + i) * 512); \
    SSTAGE_B(js_, sS_);                                                        \
    __builtin_amdgcn_s_setprio(1);                                             \
    _Pragma("unroll")                                                          \
    for (int mi = 0; mi < 4; ++mi)                                             \
      _Pragma("unroll")                                                        \
      for (int nj = 0; nj < 4; ++nj)                                           \
        acc[4 + mi][nj] = __builtin_amdgcn_mfma_f32_16x16x32_bf16(             \
            CA1[mi], CB[nj], acc[4 + mi][nj], 0, 0, 0);                        \
    __builtin_amdgcn_s_setprio(0);                                             \
  } while (0)

  for (int j = 0; j < NS; j += 2) {
    SITER(j, bP, aP0, aP1, bQ, aQ0, aQ1);
    SITER(j + 1, bQ, aQ0, aQ1, bP, aP0, aP1);
  }
#undef SITER
#undef SSTAGE_A
#undef SSTAGE_B
}

// ---------------------------------------------------------------------------
// Kernels
// ---------------------------------------------------------------------------

__global__ void convert_x_kernel(const float* __restrict__ x, u16* __restrict__ xb) {
  int i = blockIdx.x * 256 + threadIdx.x;       // 2,097,152 threads * 4 floats
  float4 f = ((const float4*)x)[i];
  u16x4 o = { f2bf(f.x), f2bf(f.y), f2bf(f.z), f2bf(f.w) };
  ((u16x4*)xb)[i] = o;
}

// W[m][d][e] f32 -> Wt[m][e][d] bf16 (LDS-tiled transpose)
__global__ void convw_kernel(const float* __restrict__ W, u16* __restrict__ wT) {
  __shared__ float tile[32][33];
  const int mtx = blockIdx.z;
  const int e0 = blockIdx.x * 32, d0 = blockIdx.y * 32;
  const int tx = threadIdx.x, ty = threadIdx.y;
  const float* Wm = W + (size_t)mtx * 262144;
#pragma unroll
  for (int i = 0; i < 32; i += 8)
    tile[ty + i][tx] = Wm[(size_t)(d0 + ty + i) * 512 + e0 + tx];
  __syncthreads();
  u16* T = wT + (size_t)mtx * 262144;
#pragma unroll
  for (int i = 0; i < 32; i += 8)
    T[(size_t)(e0 + ty + i) * 512 + d0 + tx] = f2bf(tile[tx][ty + i]);
}

// QKV: xb[16384,512] . wT[1536,512]^T via 256x128 tiles (single frag set).
// Swizzle: xcd = id&7 owns batch xcd's m-rows: x 2MB + wT 1.5MB L2-resident.
__global__ __launch_bounds__(512, 4) void gemm_qkv128_kernel(
    const u16* __restrict__ xb, const u16* __restrict__ wT,
    u16* __restrict__ qb, u16* __restrict__ kb, u16* __restrict__ vt)
{
  __shared__ __align__(16) u16 lds[36864];   // 72 KB
  const int id = blockIdx.x;                 // 768 blocks
  const int xcd = id & 7, t = id >> 3;       // t: 0..95
  const int n0 = (t % 12) * 128;
  const int m0 = (xcd * 8 + t / 12) * 256;
  f32x4 acc[4][4] = {};
  gemm8p_256x128<512>(xb + (size_t)m0 * 512, wT + (size_t)n0 * 512, lds, acc);

  const int tid = threadIdx.x, w = tid >> 6, l = tid & 63;
  const int wm = w >> 1, wn = w & 1;
  const int which = n0 >> 9;                 // 0=q 1=k 2=v
  const int eb = (n0 & 511) + wn * 64 + (l & 15);
  const int rb = m0 + wm * 64 + (l >> 4) * 4;
  if (which < 2) {
    u16* dst = which ? kb : qb;
#pragma unroll
    for (int mi = 0; mi < 4; ++mi)
#pragma unroll
      for (int nj = 0; nj < 4; ++nj) {
        const int row = rb + mi * 16;
        const int col = eb + nj * 16;
#pragma unroll
        for (int r = 0; r < 4; ++r)
          dst[(size_t)(row + r) * 512 + col] = f2bf(acc[mi][nj][r]);
      }
  } else {
#pragma unroll
    for (int mi = 0; mi < 4; ++mi)
#pragma unroll
      for (int nj = 0; nj < 4; ++nj) {
        const int s = rb + mi * 16;            // global row (b*2048+s)
        const int b = s >> 11, sl = s & 2047;
        const int e = eb + nj * 16;
        u16x4 pk;
#pragma unroll
        for (int r = 0; r < 4; ++r) pk[r] = f2bf(acc[mi][nj][r]);
        *(u16x4*)(vt + (size_t)b * 1048576 + (size_t)e * 2048 + sl) = pk;
      }
  }
}

// P[z] = exp(Q[z].K[z]^T * 0.125) -> bf16 (unnormalized; pv divides by
// rowsum). 256x256 4-slot pp tiles; 512 blocks = 2 rounds; z = id&7.
__global__ __launch_bounds__(512, 2) void gemm_scores256_kernel(
    const u16* __restrict__ qb, const u16* __restrict__ kb, u16* __restrict__ attn)
{
  __shared__ __align__(16) u16 lds[65536];   // 128 KB
  const int id = blockIdx.x;                 // 512 blocks
  const int z = id & 7, t = id >> 3;         // t: 0..63
  const int n0 = (t & 7) * 256;
  const int m0 = (t >> 3) * 256;
  f32x4 acc[8][4] = {};
  gemm8p_256sq_pp4<512>(qb + (size_t)z * 1048576 + (size_t)m0 * 512,
                        kb + (size_t)z * 1048576 + (size_t)n0 * 512, lds, acc);

  const int tid = threadIdx.x, w = tid >> 6, l = tid & 63;
  const int wm = w >> 2, wn = w & 3;
  u16* C = attn + (size_t)z * 4194304;
  const int rb = m0 + wm * 128 + (l >> 4) * 4;
  const int cb = n0 + wn * 64 + (l & 15);
#pragma unroll
  for (int mi = 0; mi < 8; ++mi)
#pragma unroll
    for (int nj = 0; nj < 4; ++nj) {
      const int row = rb + mi * 16;
      const int col = cb + nj * 16;
#pragma unroll
      for (int r = 0; r < 4; ++r)
        C[(size_t)(row + r) * 2048 + col] = f2bf(__expf(acc[mi][nj][r] * 0.125f));
    }
}

// out[z] = (P[z].V[z]) / rowsum. 4-slot pp mainloop + MFMA rowsum:
// acc5[mi] += A x ones; C-layout puts row rb+mi*16+(l>>4)*4+r's sum in
// acc5[mi][r] on the normalizing lane (no shfl).
__global__ __launch_bounds__(512, 2) void gemm_pv8p_kernel(
    const u16* __restrict__ attn, const u16* __restrict__ vt, float* __restrict__ out)
{
  __shared__ __align__(16) u16 lds[49152];   // 96 KB
  const int id = blockIdx.x;                 // 256 blocks
  const int z = id & 7;                      // id%8 = XCD (T1): one z per XCD
  const int j = id >> 3;                     // 0..31
  const int n0 = (j & 3) * 128;              // 4 n-tiles
  const int m0 = (j >> 2) * 256;             // 8 m-tiles
  f32x4 acc[4][4] = {};
  f32x4 acc5[4] = {};
  gemm128_pp4<2048>(attn + (size_t)z * 4194304 + (size_t)m0 * 2048,
                    vt + (size_t)z * 1048576 + (size_t)n0 * 2048, lds, acc, acc5);

  const int tid = threadIdx.x, w = tid >> 6, l = tid & 63;
  const int wm = w >> 1, wn = w & 1;
  const int rb = m0 + wm * 64 + (l >> 4) * 4;
  const int cb = n0 + wn * 64 + (l & 15);
  float* C = out + (size_t)z * 1048576;
#pragma unroll
  for (int mi = 0; mi < 4; ++mi)
#pragma unroll
    for (int r = 0; r < 4; ++r) {
      const float inv = 1.f / acc5[mi][r];
      const int row = rb + mi * 16 + r;
#pragma unroll
      for (int nj = 0; nj < 4; ++nj)
        C[(size_t)row * 512 + cb + nj * 16] = acc[mi][nj][r] * inv;
    }
}

// ---------------------------------------------------------------------------
extern "C" void kernel_launch(void* const* d_in, const int* in_sizes, int n_in,
                              void* d_out, int out_size, void* d_ws, size_t ws_size,
                              hipStream_t stream) {
  const float* x = (const float*)d_in[0];   // [8,2048,512]
  const float* W = (const float*)d_in[1];   // [3,512,512]
  float* out = (float*)d_out;               // [8,2048,512]

  if (ws_size < 117440512) return;          // 112 MiB needed
  u16* wsu  = (u16*)d_ws;
  u16* qb   = wsu;
  u16* kb   = qb + 8388608;
  u16* vt   = kb + 8388608;
  u16* attn = vt + 8388608;
  u16* xb   = attn;                         // alias: dead before scores written
  u16* wT   = attn + 8388608;               // alias: dead before scores written

  convert_x_kernel<<<8192, 256, 0, stream>>>(x, xb);
  convw_kernel<<<dim3(16, 16, 3), dim3(32, 8), 0, stream>>>(W, wT);
  gemm_qkv128_kernel<<<768, 512, 0, stream>>>(xb, wT, qb, kb, vt);
  gemm_scores256_kernel<<<512, 512, 0, stream>>>(qb, kb, attn);
  gemm_pv8p_kernel<<<256, 512, 0, stream>>>(attn, vt, out);
}

// Round 19
// 123.935 us; speedup vs baseline: 2.2034x; 1.0003x over previous
//
#include <hip/hip_runtime.h>

// SelfAttention: x[8,2048,512] f32, W[3,512,512] f32 -> out[8,2048,512] f32
// scale = 1/sqrt(64) = 0.125
//
// R19: R18 + convert_x gets the same XCD-ownership swizzle as qkv
// (block id&7 = batch): writer-XCD == reader-XCD for the 2MB xb panel,
// so qkv finds xb L2-warm (completes the chain convert->qkv->scores->pv
// that z/xcd ownership already established between the GEMMs).
// Everything else identical to R18 (124.0us best).

typedef unsigned short u16;
typedef unsigned int u32;

using bf16x8 = __attribute__((ext_vector_type(8))) short;   // 8 bf16 (4 VGPRs)
using f32x4  = __attribute__((ext_vector_type(4))) float;
using u16x4  = __attribute__((ext_vector_type(4))) u16;

__device__ __forceinline__ u16 f2bf(float f) {
  u32 u = __float_as_uint(f);
  u32 r = (u + 0x7FFFu + ((u >> 16) & 1u)) >> 16;   // RNE
  return (u16)r;
}
__device__ __forceinline__ float bf2f(u16 h) {
  return __uint_as_float(((u32)h) << 16);
}

#define GLL16(src, dst)                                                        \
  __builtin_amdgcn_global_load_lds(                                            \
      (const __attribute__((address_space(1))) void*)(src),                    \
      (__attribute__((address_space(3))) void*)(dst), 16, 0, 0)

// ---------------------------------------------------------------------------
// 256x128 single-frag-set mainloop (qkv): 8 waves 4Mx2N, acc[4][4], 3-slot
// BK=32, gate vmcnt(3)+barrier. bounds(512,4), 72KB -> 2 blk/CU.
// ---------------------------------------------------------------------------
template <int K>
__device__ __forceinline__ void gemm8p_256x128(
    const u16* __restrict__ A0, const u16* __restrict__ B0,
    u16* lds, f32x4 (&acc)[4][4])
{
  const int tid = threadIdx.x;
  const int w = tid >> 6, l = tid & 63;
  const int wm = w >> 1, wn = w & 1;
  const int fr = l & 15;
  const int laneChunk = ((l >> 4) ^ ((fr >> 1) & 3)) << 3;
  const int laneA = (wm * 64 + fr) * 32 + laneChunk;
  const int laneB = (wn * 64 + fr) * 32 + laneChunk;
  u16* const ldsA = lds;                 // 3 slots x 8192 u16 (16 KB)
  u16* const ldsB = lds + 24576;         // 3 slots x 4096 u16 (8 KB)

  const int chunkS = ((tid & 3) ^ ((tid >> 3) & 3)) << 3;
  const int r0 = tid >> 2;               // 0..127
  const u16* const sA0 = A0 + (size_t)r0 * K + chunkS;
  const u16* const sA1 = A0 + (size_t)(r0 + 128) * K + chunkS;
  const u16* const sB0 = B0 + (size_t)r0 * K + chunkS;
  const int dOf = w * 512;

#define PSTAGE_A(j, slot) do {                                                 \
    u16* d_ = ldsA + (slot) * 8192 + dOf;                                      \
    GLL16(sA0 + (j) * 32, d_);                                                 \
    GLL16(sA1 + (j) * 32, d_ + 4096);                                          \
  } while (0)
#define PSTAGE_B(j, slot) do {                                                 \
    u16* d_ = ldsB + (slot) * 4096 + dOf;                                      \
    GLL16(sB0 + (j) * 32, d_);                                                 \
  } while (0)

  PSTAGE_B(0, 0); PSTAGE_A(0, 0);
  PSTAGE_B(1, 1); PSTAGE_A(1, 1);

  constexpr int NS = K / 32;
  int slot = 0;
  for (int j = 0; j < NS; ++j) {
    const int jn = (j + 2 < NS) ? (j + 2) : (NS - 1);
    int slotn = slot + 2; if (slotn >= 3) slotn -= 3;

    asm volatile("s_waitcnt vmcnt(3)\n\ts_barrier" ::: "memory");

    const u16* const Ab = ldsA + slot * 8192;
    const u16* const Bb = ldsB + slot * 4096;
    bf16x8 a[4], b[4];
#pragma unroll
    for (int i = 0; i < 4; ++i) a[i] = *(const bf16x8*)(Ab + laneA + i * 512);
#pragma unroll
    for (int i = 0; i < 4; ++i) b[i] = *(const bf16x8*)(Bb + laneB + i * 512);
    PSTAGE_B(jn, slotn);
    __builtin_amdgcn_s_setprio(1);
#pragma unroll
    for (int mi = 0; mi < 2; ++mi)
#pragma unroll
      for (int nj = 0; nj < 4; ++nj)
        acc[mi][nj] = __builtin_amdgcn_mfma_f32_16x16x32_bf16(a[mi], b[nj], acc[mi][nj], 0, 0, 0);
    __builtin_amdgcn_s_setprio(0);
    PSTAGE_A(jn, slotn);
    __builtin_amdgcn_s_setprio(1);
#pragma unroll
    for (int mi = 2; mi < 4; ++mi)
#pragma unroll
      for (int nj = 0; nj < 4; ++nj)
        acc[mi][nj] = __builtin_amdgcn_mfma_f32_16x16x32_bf16(a[mi], b[nj], acc[mi][nj], 0, 0, 0);
    __builtin_amdgcn_s_setprio(0);

    slot = (slot == 2) ? 0 : slot + 1;
  }
#undef PSTAGE_A
#undef PSTAGE_B
}

// ---------------------------------------------------------------------------
// 256x128 4-slot ping-pong mainloop (pv): frags[j+1] read during MFMA[j];
// stage slab j+3 into slot (j+3)&3; gate vmcnt(3) only (4-slot: read slot
// rewritten 4 slabs later). ROWSUM: acc5 += A x ones (matrix-pipe rowsum).
// LDS 96KB; bounds(512,2) (pv grid 256 = 1 blk/CU anyway).
// ---------------------------------------------------------------------------
template <int K>
__device__ __forceinline__ void gemm128_pp4(
    const u16* __restrict__ A0, const u16* __restrict__ B0,
    u16* lds, f32x4 (&acc)[4][4], f32x4 (&acc5)[4])
{
  const int tid = threadIdx.x;
  const int w = tid >> 6, l = tid & 63;
  const int wm = w >> 1, wn = w & 1;
  const int fr = l & 15;
  const int laneChunk = ((l >> 4) ^ ((fr >> 1) & 3)) << 3;
  const int laneA = (wm * 64 + fr) * 32 + laneChunk;
  const int laneB = (wn * 64 + fr) * 32 + laneChunk;
  u16* const ldsA = lds;                 // 4 slots x 8192 u16 (16 KB)
  u16* const ldsB = lds + 32768;         // 4 slots x 4096 u16 (8 KB)

  const int chunkS = ((tid & 3) ^ ((tid >> 3) & 3)) << 3;
  const int r0 = tid >> 2;               // 0..127
  const u16* const sA0 = A0 + (size_t)r0 * K + chunkS;
  const u16* const sA1 = A0 + (size_t)(r0 + 128) * K + chunkS;
  const u16* const sB0 = B0 + (size_t)r0 * K + chunkS;
  const int dOf = w * 512;

  bf16x8 bOnes;
#pragma unroll
  for (int i = 0; i < 8; ++i) bOnes[i] = (short)0x3F80;   // bf16 1.0

#define PSTAGE_A(j, slot) do {                                                 \
    u16* d_ = ldsA + (slot) * 8192 + dOf;                                      \
    GLL16(sA0 + (j) * 32, d_);                                                 \
    GLL16(sA1 + (j) * 32, d_ + 4096);                                          \
  } while (0)
#define PSTAGE_B(j, slot) do {                                                 \
    u16* d_ = ldsB + (slot) * 4096 + dOf;                                      \
    GLL16(sB0 + (j) * 32, d_);                                                 \
  } while (0)

  constexpr int NS = K / 32;
  bf16x8 aP[4], bP[4], aQ[4], bQ[4];     // statically-named ping-pong sets

  PSTAGE_B(0, 0); PSTAGE_A(0, 0);
  PSTAGE_B(1, 1); PSTAGE_A(1, 1);
  PSTAGE_B(2, 2); PSTAGE_A(2, 2);
  asm volatile("s_waitcnt vmcnt(6)\n\ts_barrier" ::: "memory");
#pragma unroll
  for (int i = 0; i < 4; ++i) aP[i] = *(const bf16x8*)(ldsA + laneA + i * 512);
#pragma unroll
  for (int i = 0; i < 4; ++i) bP[i] = *(const bf16x8*)(ldsB + laneB + i * 512);

#define KITER(jj, CA, CB, NA, NB) do {                                         \
    const int js_ = ((jj) + 3 < NS) ? (jj) + 3 : NS - 1;                       \
    const int sS_ = ((jj) + 3) & 3;                                            \
    const int sR_ = ((jj) + 1) & 3;                                            \
    asm volatile("s_waitcnt vmcnt(3)\n\ts_barrier" ::: "memory");              \
    const u16* const Ab_ = ldsA + sR_ * 8192;                                  \
    const u16* const Bb_ = ldsB + sR_ * 4096;                                  \
    _Pragma("unroll")                                                          \
    for (int i = 0; i < 4; ++i) NB[i] = *(const bf16x8*)(Bb_ + laneB + i * 512); \
    _Pragma("unroll")                                                          \
    for (int i = 0; i < 4; ++i) NA[i] = *(const bf16x8*)(Ab_ + laneA + i * 512); \
    PSTAGE_B(js_, sS_);                                                        \
    __builtin_amdgcn_s_setprio(1);                                             \
    _Pragma("unroll")                                                          \
    for (int mi = 0; mi < 2; ++mi)                                             \
      _Pragma("unroll")                                                        \
      for (int nj = 0; nj < 4; ++nj)                                           \
        acc[mi][nj] = __builtin_amdgcn_mfma_f32_16x16x32_bf16(                 \
            CA[mi], CB[nj], acc[mi][nj], 0, 0, 0);                             \
    __builtin_amdgcn_s_setprio(0);                                             \
    PSTAGE_A(js_, sS_);                                                        \
    __builtin_amdgcn_s_setprio(1);                                             \
    _Pragma("unroll")                                                          \
    for (int mi = 2; mi < 4; ++mi)                                             \
      _Pragma("unroll")                                                        \
      for (int nj = 0; nj < 4; ++nj)                                           \
        acc[mi][nj] = __builtin_amdgcn_mfma_f32_16x16x32_bf16(                 \
            CA[mi], CB[nj], acc[mi][nj], 0, 0, 0);                             \
    _Pragma("unroll")                                                          \
    for (int mi = 0; mi < 4; ++mi)                                             \
      acc5[mi] = __builtin_amdgcn_mfma_f32_16x16x32_bf16(                      \
          CA[mi], bOnes, acc5[mi], 0, 0, 0);                                   \
    __builtin_amdgcn_s_setprio(0);                                             \
  } while (0)

  for (int j = 0; j < NS; j += 2) {      // NS even; static reg names
    KITER(j, aP, bP, aQ, bQ);
    KITER(j + 1, aQ, bQ, aP, bP);
  }
#undef KITER
#undef PSTAGE_A
#undef PSTAGE_B
}

// ---------------------------------------------------------------------------
// 256x256 4-slot ping-pong mainloop (scores): gate vmcnt(4) only.
// LDS 128KB, 1 blk/CU.
// ---------------------------------------------------------------------------
template <int K>
__device__ __forceinline__ void gemm8p_256sq_pp4(
    const u16* __restrict__ A0, const u16* __restrict__ B0,
    u16* lds, f32x4 (&acc)[8][4])
{
  const int tid = threadIdx.x;
  const int w = tid >> 6, l = tid & 63;
  const int wm = w >> 2, wn = w & 3;
  const int fr = l & 15;
  const int laneChunk = ((l >> 4) ^ ((fr >> 1) & 3)) << 3;
  const int laneA = (wm * 128 + fr) * 32 + laneChunk;
  const int laneB = (wn * 64 + fr) * 32 + laneChunk;
  u16* const ldsA = lds;                 // 4 slots x 8192 u16 (16 KB)
  u16* const ldsB = lds + 32768;         // 4 slots x 8192 u16 (16 KB)

  const int chunkS = ((tid & 3) ^ ((tid >> 3) & 3)) << 3;
  const int r0 = tid >> 2;               // 0..127
  const u16* const sA0 = A0 + (size_t)r0 * K + chunkS;
  const u16* const sA1 = A0 + (size_t)(r0 + 128) * K + chunkS;
  const u16* const sB0 = B0 + (size_t)r0 * K + chunkS;
  const u16* const sB1 = B0 + (size_t)(r0 + 128) * K + chunkS;
  const int dOf = w * 512;

#define SSTAGE_A(j, slot) do {                                                 \
    u16* d_ = ldsA + (slot) * 8192 + dOf;                                      \
    GLL16(sA0 + (j) * 32, d_);                                                 \
    GLL16(sA1 + (j) * 32, d_ + 4096);                                          \
  } while (0)
#define SSTAGE_B(j, slot) do {                                                 \
    u16* d_ = ldsB + (slot) * 8192 + dOf;                                      \
    GLL16(sB0 + (j) * 32, d_);                                                 \
    GLL16(sB1 + (j) * 32, d_ + 4096);                                          \
  } while (0)

  constexpr int NS = K / 32;
  bf16x8 bP[4], aP0[4], aP1[4], bQ[4], aQ0[4], aQ1[4];

  SSTAGE_B(0, 0); SSTAGE_A(0, 0);
  SSTAGE_B(1, 1); SSTAGE_A(1, 1);
  SSTAGE_B(2, 2); SSTAGE_A(2, 2);
  asm volatile("s_waitcnt vmcnt(8)\n\ts_barrier" ::: "memory");
#pragma unroll
  for (int i = 0; i < 4; ++i) bP[i]  = *(const bf16x8*)(ldsB + laneB + i * 512);
#pragma unroll
  for (int i = 0; i < 4; ++i) aP0[i] = *(const bf16x8*)(ldsA + laneA + i * 512);
#pragma unroll
  for (int i = 0; i < 4; ++i) aP1[i] = *(const bf16x8*)(ldsA + laneA + (4 + i) * 512);

#define SITER(jj, CB, CA0, CA1, NB, NA0, NA1) do {                             \
    const int js_ = ((jj) + 3 < NS) ? (jj) + 3 : NS - 1;                       \
    const int sS_ = ((jj) + 3) & 3;                                            \
    const int sR_ = ((jj) + 1) & 3;                                            \
    asm volatile("s_waitcnt vmcnt(4)\n\ts_barrier" ::: "memory");              \
    const u16* const Ab_ = ldsA + sR_ * 8192;                                  \
    const u16* const Bb_ = ldsB + sR_ * 8192;                                  \
    _Pragma("unroll")                                                          \
    for (int i = 0; i < 4; ++i) NB[i]  = *(const bf16x8*)(Bb_ + laneB + i * 512); \
    _Pragma("unroll")                                                          \
    for (int i = 0; i < 4; ++i) NA0[i] = *(const bf16x8*)(Ab_ + laneA + i * 512); \
    SSTAGE_A(js_, sS_);                                                        \
    __builtin_amdgcn_s_setprio(1);                                             \
    _Pragma("unroll")                                                          \
    for (int mi = 0; mi < 4; ++mi)                                             \
      _Pragma("unroll")                                                        \
      for (int nj = 0; nj < 4; ++nj)                                           \
        acc[mi][nj] = __builtin_amdgcn_mfma_f32_16x16x32_bf16(                 \
            CA0[mi], CB[nj], acc[mi][nj], 0, 0, 0);                            \
    __builtin_amdgcn_s_setprio(0);                                             \
    _Pragma("unroll")                                                          \
    for (int i = 0; i < 4; ++i) NA1[i] = *(const bf16x8*)(Ab_ + laneA + (4 + i) * 512); \
    SSTAGE_B(js_, sS_);                                                        \
    __builtin_amdgcn_s_setprio(1);                                             \
    _Pragma("unroll")                                                          \
    for (int mi = 0; mi < 4; ++mi)                                             \
      _Pragma("unroll")                                                        \
      for (int nj = 0; nj < 4; ++nj)                                           \
        acc[4 + mi][nj] = __builtin_amdgcn_mfma_f32_16x16x32_bf16(             \
            CA1[mi], CB[nj], acc[4 + mi][nj], 0, 0, 0);                        \
    __builtin_amdgcn_s_setprio(0);                                             \
  } while (0)

  for (int j = 0; j < NS; j += 2) {
    SITER(j, bP, aP0, aP1, bQ, aQ0, aQ1);
    SITER(j + 1, bQ, aQ0, aQ1, bP, aP0, aP1);
  }
#undef SITER
#undef SSTAGE_A
#undef SSTAGE_B
}

// ---------------------------------------------------------------------------
// Kernels
// ---------------------------------------------------------------------------

// convert x f32 -> bf16. XCD-ownership swizzle: block id&7 = batch b ->
// the 2MB xb panel is written by (and stays L2-resident on) the same XCD
// whose qkv blocks read it. 1024 blocks per batch; bijective on 8192.
__global__ void convert_x_kernel(const float* __restrict__ x, u16* __restrict__ xb) {
  const int b = blockIdx.x & 7, t = blockIdx.x >> 3;   // t: 0..1023
  const size_t i = ((size_t)b * 1024 + t) * 256 + threadIdx.x;
  float4 f = ((const float4*)x)[i];
  u16x4 o = { f2bf(f.x), f2bf(f.y), f2bf(f.z), f2bf(f.w) };
  ((u16x4*)xb)[i] = o;
}

// W[m][d][e] f32 -> Wt[m][e][d] bf16 (LDS-tiled transpose)
__global__ void convw_kernel(const float* __restrict__ W, u16* __restrict__ wT) {
  __shared__ float tile[32][33];
  const int mtx = blockIdx.z;
  const int e0 = blockIdx.x * 32, d0 = blockIdx.y * 32;
  const int tx = threadIdx.x, ty = threadIdx.y;
  const float* Wm = W + (size_t)mtx * 262144;
#pragma unroll
  for (int i = 0; i < 32; i += 8)
    tile[ty + i][tx] = Wm[(size_t)(d0 + ty + i) * 512 + e0 + tx];
  __syncthreads();
  u16* T = wT + (size_t)mtx * 262144;
#pragma unroll
  for (int i = 0; i < 32; i += 8)
    T[(size_t)(e0 + ty + i) * 512 + d0 + tx] = f2bf(tile[tx][ty + i]);
}

// QKV: xb[16384,512] . wT[1536,512]^T via 256x128 tiles (single frag set).
// Swizzle: xcd = id&7 owns batch xcd's m-rows: x 2MB + wT 1.5MB L2-resident.
__global__ __launch_bounds__(512, 4) void gemm_qkv128_kernel(
    const u16* __restrict__ xb, const u16* __restrict__ wT,
    u16* __restrict__ qb, u16* __restrict__ kb, u16* __restrict__ vt)
{
  __shared__ __align__(16) u16 lds[36864];   // 72 KB
  const int id = blockIdx.x;                 // 768 blocks
  const int xcd = id & 7, t = id >> 3;       // t: 0..95
  const int n0 = (t % 12) * 128;
  const int m0 = (xcd * 8 + t / 12) * 256;
  f32x4 acc[4][4] = {};
  gemm8p_256x128<512>(xb + (size_t)m0 * 512, wT + (size_t)n0 * 512, lds, acc);

  const int tid = threadIdx.x, w = tid >> 6, l = tid & 63;
  const int wm = w >> 1, wn = w & 1;
  const int which = n0 >> 9;                 // 0=q 1=k 2=v
  const int eb = (n0 & 511) + wn * 64 + (l & 15);
  const int rb = m0 + wm * 64 + (l >> 4) * 4;
  if (which < 2) {
    u16* dst = which ? kb : qb;
#pragma unroll
    for (int mi = 0; mi < 4; ++mi)
#pragma unroll
      for (int nj = 0; nj < 4; ++nj) {
        const int row = rb + mi * 16;
        const int col = eb + nj * 16;
#pragma unroll
        for (int r = 0; r < 4; ++r)
          dst[(size_t)(row + r) * 512 + col] = f2bf(acc[mi][nj][r]);
      }
  } else {
#pragma unroll
    for (int mi = 0; mi < 4; ++mi)
#pragma unroll
      for (int nj = 0; nj < 4; ++nj) {
        const int s = rb + mi * 16;            // global row (b*2048+s)
        const int b = s >> 11, sl = s & 2047;
        const int e = eb + nj * 16;
        u16x4 pk;
#pragma unroll
        for (int r = 0; r < 4; ++r) pk[r] = f2bf(acc[mi][nj][r]);
        *(u16x4*)(vt + (size_t)b * 1048576 + (size_t)e * 2048 + sl) = pk;
      }
  }
}

// P[z] = exp(Q[z].K[z]^T * 0.125) -> bf16 (unnormalized; pv divides by
// rowsum). 256x256 4-slot pp tiles; 512 blocks = 2 rounds; z = id&7.
__global__ __launch_bounds__(512, 2) void gemm_scores256_kernel(
    const u16* __restrict__ qb, const u16* __restrict__ kb, u16* __restrict__ attn)
{
  __shared__ __align__(16) u16 lds[65536];   // 128 KB
  const int id = blockIdx.x;                 // 512 blocks
  const int z = id & 7, t = id >> 3;         // t: 0..63
  const int n0 = (t & 7) * 256;
  const int m0 = (t >> 3) * 256;
  f32x4 acc[8][4] = {};
  gemm8p_256sq_pp4<512>(qb + (size_t)z * 1048576 + (size_t)m0 * 512,
                        kb + (size_t)z * 1048576 + (size_t)n0 * 512, lds, acc);

  const int tid = threadIdx.x, w = tid >> 6, l = tid & 63;
  const int wm = w >> 2, wn = w & 3;
  u16* C = attn + (size_t)z * 4194304;
  const int rb = m0 + wm * 128 + (l >> 4) * 4;
  const int cb = n0 + wn * 64 + (l & 15);
#pragma unroll
  for (int mi = 0; mi < 8; ++mi)
#pragma unroll
    for (int nj = 0; nj < 4; ++nj) {
      const int row = rb + mi * 16;
      const int col = cb + nj * 16;
#pragma unroll
      for (int r = 0; r < 4; ++r)
        C[(size_t)(row + r) * 2048 + col] = f2bf(__expf(acc[mi][nj][r] * 0.125f));
    }
}

// out[z] = (P[z].V[z]) / rowsum. 4-slot pp mainloop + MFMA rowsum:
// acc5[mi] += A x ones; C-layout puts row rb+mi*16+(l>>4)*4+r's sum in
// acc5[mi][r] on the normalizing lane (no shfl).
__global__ __launch_bounds__(512, 2) void gemm_pv8p_kernel(
    const u16* __restrict__ attn, const u16* __restrict__ vt, float* __restrict__ out)
{
  __shared__ __align__(16) u16 lds[49152];   // 96 KB
  const int id = blockIdx.x;                 // 256 blocks
  const int z = id & 7;                      // id%8 = XCD (T1): one z per XCD
  const int j = id >> 3;                     // 0..31
  const int n0 = (j & 3) * 128;              // 4 n-tiles
  const int m0 = (j >> 2) * 256;             // 8 m-tiles
  f32x4 acc[4][4] = {};
  f32x4 acc5[4] = {};
  gemm128_pp4<2048>(attn + (size_t)z * 4194304 + (size_t)m0 * 2048,
                    vt + (size_t)z * 1048576 + (size_t)n0 * 2048, lds, acc, acc5);

  const int tid = threadIdx.x, w = tid >> 6, l = tid & 63;
  const int wm = w >> 1, wn = w & 1;
  const int rb = m0 + wm * 64 + (l >> 4) * 4;
  const int cb = n0 + wn * 64 + (l & 15);
  float* C = out + (size_t)z * 1048576;
#pragma unroll
  for (int mi = 0; mi < 4; ++mi)
#pragma unroll
    for (int r = 0; r < 4; ++r) {
      const float inv = 1.f / acc5[mi][r];
      const int row = rb + mi * 16 + r;
#pragma unroll
      for (int nj = 0; nj < 4; ++nj)
        C[(size_t)row * 512 + cb + nj * 16] = acc[mi][nj][r] * inv;
    }
}

// ---------------------------------------------------------------------------
extern "C" void kernel_launch(void* const* d_in, const int* in_sizes, int n_in,
                              void* d_out, int out_size, void* d_ws, size_t ws_size,
                              hipStream_t stream) {
  const float* x = (const float*)d_in[0];   // [8,2048,512]
  const float* W = (const float*)d_in[1];   // [3,512,512]
  float* out = (float*)d_out;               // [8,2048,512]

  if (ws_size < 117440512) return;          // 112 MiB needed
  u16* wsu  = (u16*)d_ws;
  u16* qb   = wsu;
  u16* kb   = qb + 8388608;
  u16* vt   = kb + 8388608;
  u16* attn = vt + 8388608;
  u16* xb   = attn;                         // alias: dead before scores written
  u16* wT   = attn + 8388608;               // alias: dead before scores written

  convert_x_kernel<<<8192, 256, 0, stream>>>(x, xb);
  convw_kernel<<<dim3(16, 16, 3), dim3(32, 8), 0, stream>>>(W, wT);
  gemm_qkv128_kernel<<<768, 512, 0, stream>>>(xb, wT, qb, kb, vt);
  gemm_scores256_kernel<<<512, 512, 0, stream>>>(qb, kb, attn);
  gemm_pv8p_kernel<<<256, 512, 0, stream>>>(attn, vt, out);
}